// Round 1
// baseline (2010.749 us; speedup 1.0000x reference)
//
#include <hip/hip_runtime.h>
#include <cstdint>
#include <cstddef>

#define NOBJ 100

// ---------------------------------------------------------------------------
// fp32 tiled GEMM: C[M][N] = A[M][K] @ B
//   BT=false: B is [K][N] row-major
//   BT=true : B is [N][K] row-major (we multiply by B^T)
// 128x128 tile, BK=8, 256 threads, 8x8 per-thread microtile.
// M%128==0, N%128==0, K%8==0 hold for all our shapes (25600/1024).
// ---------------------------------------------------------------------------
template<bool BT>
__global__ __launch_bounds__(256)
void gemm128x128(const float* __restrict__ A, const float* __restrict__ B,
                 float* __restrict__ C, int M, int N, int K) {
  __shared__ __align__(16) float as[8][128];   // as[k][m]
  __shared__ __align__(16) float bs[8][128];   // bs[k][n]
  const int t  = threadIdx.x;
  const int m0 = blockIdx.y * 128;
  const int n0 = blockIdx.x * 128;
  const int tr = (t >> 4) * 8;    // row offset in tile
  const int tc = (t & 15) * 8;    // col offset in tile
  const int arow = t >> 1;        // 0..127
  const int apos = (t & 1) * 4;   // 0 or 4
  const int brow = t >> 5;        // 0..7
  const int bcol = (t & 31) * 4;  // 0..124

  float acc[8][8];
#pragma unroll
  for (int i = 0; i < 8; ++i)
#pragma unroll
    for (int j = 0; j < 8; ++j) acc[i][j] = 0.f;

  for (int kc = 0; kc < K; kc += 8) {
    const float4 av = *(const float4*)(A + (size_t)(m0 + arow) * K + kc + apos);
    float4 bv;
    if (!BT) bv = *(const float4*)(B + (size_t)(kc + brow) * N + n0 + bcol);
    else     bv = *(const float4*)(B + (size_t)(n0 + arow) * K + kc + apos);
    __syncthreads();                       // previous iter's reads done
    as[apos + 0][arow] = av.x;
    as[apos + 1][arow] = av.y;
    as[apos + 2][arow] = av.z;
    as[apos + 3][arow] = av.w;
    if (!BT) {
      *(float4*)&bs[brow][bcol] = bv;
    } else {
      bs[apos + 0][arow] = bv.x;
      bs[apos + 1][arow] = bv.y;
      bs[apos + 2][arow] = bv.z;
      bs[apos + 3][arow] = bv.w;
    }
    __syncthreads();
#pragma unroll
    for (int kk = 0; kk < 8; ++kk) {
      float a[8], b[8];
      *(float4*)&a[0] = *(const float4*)&as[kk][tr];
      *(float4*)&a[4] = *(const float4*)&as[kk][tr + 4];
      *(float4*)&b[0] = *(const float4*)&bs[kk][tc];
      *(float4*)&b[4] = *(const float4*)&bs[kk][tc + 4];
#pragma unroll
      for (int i = 0; i < 8; ++i)
#pragma unroll
        for (int j = 0; j < 8; ++j) acc[i][j] = fmaf(a[i], b[j], acc[i][j]);
    }
  }

#pragma unroll
  for (int i = 0; i < 8; ++i) {
    float4 v0 = {acc[i][0], acc[i][1], acc[i][2], acc[i][3]};
    float4 v1 = {acc[i][4], acc[i][5], acc[i][6], acc[i][7]};
    float* cp = C + (size_t)(m0 + tr + i) * N + n0 + tc;
    *(float4*)cp       = v0;
    *(float4*)(cp + 4) = v1;
  }
}

// ---------------------------------------------------------------------------
// Per-batch fused: S = qk_b @ feat_b^T  (100x100, K=1024)
//   -> relu -> mask(graph!=0) -> softmax over n (axis=1, per column m,
//      masked zeros PARTICIPATE, matching the reference)
//   -> out_b[n][:] = sum_m S[n][m] * outp_b[m][:]
// One block per batch; 256 threads (16x16); S kept in LDS.
// LDS: 40000 (S) + 15232 (q/k staging, KC=16, pad 17) = 55232 B < 64 KB.
// ---------------------------------------------------------------------------
__global__ __launch_bounds__(256)
void attn_fused(const float* __restrict__ qk, const float* __restrict__ feat,
                const float* __restrict__ outp, const int* __restrict__ graph,
                float* __restrict__ out) {
  __shared__ float s[NOBJ * NOBJ];       // s[n*100+m]
  __shared__ float stg[2 * 112 * 17];    // qs | ks, rows padded to 112, stride 17
  float* qs = stg;
  float* ks = stg + 112 * 17;

  const int b  = blockIdx.x;
  const int t  = threadIdx.x;
  const int tn = t >> 4;    // 0..15
  const int tm = t & 15;    // 0..15

  const float* qb = qk   + (size_t)b * NOBJ * 1024;
  const float* fb = feat + (size_t)b * NOBJ * 1024;

  // zero pad rows 100..111 once (they never get overwritten by the loads)
  for (int idx = t; idx < 12 * 17; idx += 256) {
    qs[100 * 17 + idx] = 0.f;
    ks[100 * 17 + idx] = 0.f;
  }

  float acc[7][7];
#pragma unroll
  for (int i = 0; i < 7; ++i)
#pragma unroll
    for (int j = 0; j < 7; ++j) acc[i][j] = 0.f;

  // ---- phase 1: S = qk_b @ feat_b^T, K in chunks of 16 ----
  for (int kc = 0; kc < 1024; kc += 16) {
    __syncthreads();
    for (int idx = t; idx < NOBJ * 4; idx += 256) {
      const int n = idx >> 2, c4 = (idx & 3) * 4;
      const float4 qv = *(const float4*)(qb + n * 1024 + kc + c4);
      const float4 kv = *(const float4*)(fb + n * 1024 + kc + c4);
      float* qd = qs + n * 17 + c4;
      float* kd = ks + n * 17 + c4;
      qd[0] = qv.x; qd[1] = qv.y; qd[2] = qv.z; qd[3] = qv.w;
      kd[0] = kv.x; kd[1] = kv.y; kd[2] = kv.z; kd[3] = kv.w;
    }
    __syncthreads();
#pragma unroll 4
    for (int kk = 0; kk < 16; ++kk) {
      float qv[7], kv[7];
#pragma unroll
      for (int i = 0; i < 7; ++i) qv[i] = qs[(tn + 16 * i) * 17 + kk];
#pragma unroll
      for (int j = 0; j < 7; ++j) kv[j] = ks[(tm + 16 * j) * 17 + kk];
#pragma unroll
      for (int i = 0; i < 7; ++i)
#pragma unroll
        for (int j = 0; j < 7; ++j) acc[i][j] = fmaf(qv[i], kv[j], acc[i][j]);
    }
  }

  // ---- relu + adjacency mask -> s ----
  const int* gb = graph + (size_t)b * NOBJ * NOBJ;
#pragma unroll
  for (int i = 0; i < 7; ++i) {
    const int n = tn + 16 * i;
    if (n >= NOBJ) break;
#pragma unroll
    for (int j = 0; j < 7; ++j) {
      const int m = tm + 16 * j;
      if (m < NOBJ) {
        float v = acc[i][j];
        v = v > 0.f ? v : 0.f;
        s[n * NOBJ + m] = (gb[n * NOBJ + m] != 0) ? v : 0.f;
      }
    }
  }
  __syncthreads();

  // ---- softmax over n for each column m (values >= 0, so seed max with 0) ----
  if (t < NOBJ) {
    const int m = t;
    float mx = 0.f;
    for (int n = 0; n < NOBJ; ++n) mx = fmaxf(mx, s[n * NOBJ + m]);
    float sum = 0.f;
    for (int n = 0; n < NOBJ; ++n) {
      const float e = expf(s[n * NOBJ + m] - mx);
      s[n * NOBJ + m] = e;
      sum += e;
    }
    const float inv = 1.f / sum;
    for (int n = 0; n < NOBJ; ++n) s[n * NOBJ + m] *= inv;
  }
  __syncthreads();

  // ---- phase 3: out[b,n,:] = sum_m s[n][m] * outp[b,m,:] ----
  // outp tile read straight from global: per m, the 100x64 slice is shared by
  // 16 threads per float4 -> L1/L2 broadcast; no LDS staging, no barriers.
  const float* ob   = outp + (size_t)b * NOBJ * 1024;
  float*       outb = out  + (size_t)b * NOBJ * 1024;
  int nrow[7];
#pragma unroll
  for (int i = 0; i < 7; ++i) {
    const int n = tn + 16 * i;
    nrow[i] = (n < NOBJ ? n : 0) * NOBJ;   // clamped; clamped rows discarded at write
  }
  for (int oc = 0; oc < 1024; oc += 64) {
    float a[7][4];
#pragma unroll
    for (int i = 0; i < 7; ++i)
#pragma unroll
      for (int j = 0; j < 4; ++j) a[i][j] = 0.f;
    for (int m = 0; m < NOBJ; ++m) {
      const float4 ov = *(const float4*)(ob + m * 1024 + oc + tm * 4);
      float w[7];
#pragma unroll
      for (int i = 0; i < 7; ++i) w[i] = s[nrow[i] + m];
#pragma unroll
      for (int i = 0; i < 7; ++i) {
        a[i][0] = fmaf(w[i], ov.x, a[i][0]);
        a[i][1] = fmaf(w[i], ov.y, a[i][1]);
        a[i][2] = fmaf(w[i], ov.z, a[i][2]);
        a[i][3] = fmaf(w[i], ov.w, a[i][3]);
      }
    }
#pragma unroll
    for (int i = 0; i < 7; ++i) {
      const int n = tn + 16 * i;
      if (n < NOBJ) {
        float4 r = {a[i][0], a[i][1], a[i][2], a[i][3]};
        *(float4*)(outb + n * 1024 + oc + tm * 4) = r;
      }
    }
  }
}

// ---------------------------------------------------------------------------
// inputs: feature [256,100,1024] f32 | graph [256,100,100] i32 |
//         weight [1024,1024] f32 | wq [1024,1024] f32 | wk [1024,1024] f32
// out: [256,100,1024] f32
// ws layout (floats): outp[25600*1024] | qk[25600*1024] | m1[1024*1024]
//   total 213.9 MB — early-return if ws is smaller (fails validation loudly
//   instead of corrupting memory).
// ---------------------------------------------------------------------------
extern "C" void kernel_launch(void* const* d_in, const int* in_sizes, int n_in,
                              void* d_out, int out_size, void* d_ws, size_t ws_size,
                              hipStream_t stream) {
  const float* feature = (const float*)d_in[0];
  const int*   graph   = (const int*)  d_in[1];
  const float* weight  = (const float*)d_in[2];
  const float* wq      = (const float*)d_in[3];
  const float* wk      = (const float*)d_in[4];
  float* out = (float*)d_out;

  const size_t MROWS = (size_t)256 * NOBJ;        // 25600
  const size_t need  = (MROWS * 1024 * 2 + (size_t)1024 * 1024) * sizeof(float);
  if (ws_size < need) return;                     // ws too small: fail loudly

  float* outp = (float*)d_ws;                     // X @ W
  float* qkb  = outp + MROWS * 1024;              // X @ (Wq Wk^T)
  float* m1   = qkb  + MROWS * 1024;              // Wq @ Wk^T

  const dim3 blk(256);
  // M1 = Wq @ Wk^T   (1024x1024x1024, BT: use Wk^T)
  gemm128x128<true><<<dim3(8, 8), blk, 0, stream>>>(wq, wk, m1, 1024, 1024, 1024);
  // outp = X @ W     (25600x1024x1024)
  gemm128x128<false><<<dim3(8, 200), blk, 0, stream>>>(feature, weight, outp, 25600, 1024, 1024);
  // qk = X @ M1      (25600x1024x1024)
  gemm128x128<false><<<dim3(8, 200), blk, 0, stream>>>(feature, m1, qkb, 25600, 1024, 1024);
  // fused scores+softmax+aggregate, one block per batch
  attn_fused<<<dim3(256), blk, 0, stream>>>(qkb, feature, outp, graph, out);
}

// Round 2
// 981.250 us; speedup vs baseline: 2.0492x; 2.0492x over previous
//
#include <hip/hip_runtime.h>
#include <cstdint>
#include <cstddef>

#define NOBJ 100

typedef __attribute__((ext_vector_type(8))) short short8;
typedef __attribute__((ext_vector_type(4))) float f32x4;

typedef const __attribute__((address_space(1))) void* gas_cptr;
typedef __attribute__((address_space(3))) void* las_ptr;

__device__ __forceinline__ void gload_lds16(const void* g, void* l) {
  __builtin_amdgcn_global_load_lds((gas_cptr)g, (las_ptr)l, 16, 0, 0);
}

// ---- bf16 split helpers (RTN-even via integer trick; finite data only) ----
__device__ __forceinline__ unsigned short bf16_rtne(float x) {
  unsigned u = __builtin_bit_cast(unsigned, x);
  unsigned r = u + 0x7FFFu + ((u >> 16) & 1u);
  return (unsigned short)(r >> 16);
}
__device__ __forceinline__ float bf16_to_f32(unsigned short h) {
  unsigned u = ((unsigned)h) << 16;
  return __builtin_bit_cast(float, u);
}

// ---------------------------------------------------------------------------
// split_ew: f32[n] -> hi bf16[n], lo bf16[n].  n8 = n/8 (n divisible by 8).
// ---------------------------------------------------------------------------
__global__ __launch_bounds__(256)
void split_ew(const float* __restrict__ in, unsigned short* __restrict__ hi,
              unsigned short* __restrict__ lo, long long n8) {
  for (long long u = (long long)blockIdx.x * 256 + threadIdx.x; u < n8;
       u += (long long)gridDim.x * 256) {
    const float4* p = (const float4*)(in + u * 8);
    float4 v0 = p[0], v1 = p[1];
    float x[8] = {v0.x, v0.y, v0.z, v0.w, v1.x, v1.y, v1.z, v1.w};
    unsigned h[8], l[8];
#pragma unroll
    for (int j = 0; j < 8; ++j) {
      h[j] = bf16_rtne(x[j]);
      l[j] = bf16_rtne(x[j] - bf16_to_f32((unsigned short)h[j]));
    }
    uint4 hv, lv;
    hv.x = h[0] | (h[1] << 16); hv.y = h[2] | (h[3] << 16);
    hv.z = h[4] | (h[5] << 16); hv.w = h[6] | (h[7] << 16);
    lv.x = l[0] | (l[1] << 16); lv.y = l[2] | (l[3] << 16);
    lv.z = l[4] | (l[5] << 16); lv.w = l[6] | (l[7] << 16);
    *(uint4*)(hi + u * 8) = hv;
    *(uint4*)(lo + u * 8) = lv;
  }
}

// ---------------------------------------------------------------------------
// split_tr: W f32 [1024][1024] -> Wt hi/lo bf16 [1024][1024] transposed.
// ---------------------------------------------------------------------------
__global__ __launch_bounds__(256)
void split_tr(const float* __restrict__ W, unsigned short* __restrict__ thi,
              unsigned short* __restrict__ tlo) {
  __shared__ float tile[32][33];
  const int r0 = blockIdx.y * 32, c0 = blockIdx.x * 32;
  const int tx = threadIdx.x & 31, ty = threadIdx.x >> 5;
  for (int rr = ty; rr < 32; rr += 8)
    tile[rr][tx] = W[(size_t)(r0 + rr) * 1024 + c0 + tx];
  __syncthreads();
  for (int cc = ty; cc < 32; cc += 8) {
    float x = tile[tx][cc];
    unsigned short h = bf16_rtne(x);
    unsigned short l = bf16_rtne(x - bf16_to_f32(h));
    size_t o = (size_t)(c0 + cc) * 1024 + r0 + tx;   // Wt[n][k] = W[k][n]
    thi[o] = h;
    tlo[o] = l;
  }
}

// ---------------------------------------------------------------------------
// gemm_mfma3: C = A @ Bt^T via bf16 hi/lo split (3 MFMAs: hh + hl + lh).
// A hi/lo: bf16 [M][K]; Bt hi/lo: bf16 [N][K]; C f32 [M][N].
// 128x128 tile, BK=32, 4 waves (2x2), 4x4 16x16x32 fragments per wave.
// LDS linear (global_load_lds w16) with XOR slot swizzle: physical 16B-slot
// p = q ^ ((row>>1)&3) applied identically on the staging *global source*
// and the frag-read address (rule #21) -> 8-way conflict becomes 2-way(free).
// M%128==0, N%128==0, K%32==0.
// ---------------------------------------------------------------------------
__global__ __launch_bounds__(256)
void gemm_mfma3(const unsigned short* __restrict__ Ah, const unsigned short* __restrict__ Al,
                const unsigned short* __restrict__ Bh, const unsigned short* __restrict__ Bl,
                float* __restrict__ C, int M, int N, int K) {
  __shared__ unsigned short s_ah[4096], s_al[4096], s_bh[4096], s_bl[4096];
  const int t = threadIdx.x;
  const int wid = t >> 6, lane = t & 63;
  const int wr = wid >> 1, wc = wid & 1;
  const int lrow = lane & 15, q = lane >> 4;
  const int m0 = blockIdx.y * 128, n0 = blockIdx.x * 128;

  // staging: 16B unit u = t (+256 for pass 1); row = u>>2, logical slot =
  // (u&3) ^ ((row>>1)&3).  (row>>1)&3 invariant under row+=64 -> skch const.
  const int srow = t >> 2;
  const int skch = (t & 3) ^ ((t >> 3) & 3);
  const unsigned short* gAh = Ah + (size_t)(m0 + srow) * K + skch * 8;
  const unsigned short* gAl = Al + (size_t)(m0 + srow) * K + skch * 8;
  const unsigned short* gBh = Bh + (size_t)(n0 + srow) * K + skch * 8;
  const unsigned short* gBl = Bl + (size_t)(n0 + srow) * K + skch * 8;
  const size_t rstep = (size_t)64 * K;
  unsigned short* dA0 = &s_ah[wid * 512];   // wave-uniform LDS bases
  unsigned short* dA1 = &s_ah[wid * 512 + 2048];
  unsigned short* dAl0 = &s_al[wid * 512];
  unsigned short* dAl1 = &s_al[wid * 512 + 2048];
  unsigned short* dB0 = &s_bh[wid * 512];
  unsigned short* dB1 = &s_bh[wid * 512 + 2048];
  unsigned short* dBl0 = &s_bl[wid * 512];
  unsigned short* dBl1 = &s_bl[wid * 512 + 2048];

  // frag-read swizzled slot offset (shorts) — per-lane constant
  const int fq = (q ^ ((lrow >> 1) & 3)) * 8;

  f32x4 acc[4][4];
#pragma unroll
  for (int i = 0; i < 4; ++i)
#pragma unroll
    for (int j = 0; j < 4; ++j) acc[i][j] = (f32x4){0.f, 0.f, 0.f, 0.f};

  for (int kc = 0; kc < K; kc += 32) {
    gload_lds16(gAh + kc, dA0);
    gload_lds16(gAh + kc + rstep, dA1);
    gload_lds16(gAl + kc, dAl0);
    gload_lds16(gAl + kc + rstep, dAl1);
    gload_lds16(gBh + kc, dB0);
    gload_lds16(gBh + kc + rstep, dB1);
    gload_lds16(gBl + kc, dBl0);
    gload_lds16(gBl + kc + rstep, dBl1);
    __syncthreads();   // compiler drains vmcnt before s_barrier

    short8 a_h[4], a_l[4];
#pragma unroll
    for (int i = 0; i < 4; ++i) {
      const int ra = (wr * 64 + i * 16 + lrow) * 32 + fq;
      a_h[i] = *(const short8*)&s_ah[ra];
      a_l[i] = *(const short8*)&s_al[ra];
    }
#pragma unroll
    for (int j = 0; j < 4; ++j) {
      const int rb = (wc * 64 + j * 16 + lrow) * 32 + fq;
      short8 b_h = *(const short8*)&s_bh[rb];
      short8 b_l = *(const short8*)&s_bl[rb];
#pragma unroll
      for (int i = 0; i < 4; ++i) {
        acc[i][j] = __builtin_amdgcn_mfma_f32_16x16x32_bf16(a_h[i], b_h, acc[i][j], 0, 0, 0);
        acc[i][j] = __builtin_amdgcn_mfma_f32_16x16x32_bf16(a_h[i], b_l, acc[i][j], 0, 0, 0);
        acc[i][j] = __builtin_amdgcn_mfma_f32_16x16x32_bf16(a_l[i], b_h, acc[i][j], 0, 0, 0);
      }
    }
    __syncthreads();   // all waves done reading before next stage overwrites
  }

  // C/D layout (m89-verified): col = lane&15, row = (lane>>4)*4 + reg
#pragma unroll
  for (int i = 0; i < 4; ++i) {
    const int row = m0 + wr * 64 + i * 16 + q * 4;
#pragma unroll
    for (int j = 0; j < 4; ++j) {
      const int col = n0 + wc * 64 + j * 16 + lrow;
#pragma unroll
      for (int r = 0; r < 4; ++r)
        C[(size_t)(row + r) * N + col] = acc[i][j][r];
    }
  }
}

// ---------------------------------------------------------------------------
// fp32 tiled GEMM (round-1, kept for m1t and as fallback path)
// ---------------------------------------------------------------------------
template<bool BT>
__global__ __launch_bounds__(256)
void gemm128x128(const float* __restrict__ A, const float* __restrict__ B,
                 float* __restrict__ C, int M, int N, int K) {
  __shared__ __align__(16) float as[8][128];
  __shared__ __align__(16) float bs[8][128];
  const int t  = threadIdx.x;
  const int m0 = blockIdx.y * 128;
  const int n0 = blockIdx.x * 128;
  const int tr = (t >> 4) * 8;
  const int tc = (t & 15) * 8;
  const int arow = t >> 1;
  const int apos = (t & 1) * 4;
  const int brow = t >> 5;
  const int bcol = (t & 31) * 4;

  float acc[8][8];
#pragma unroll
  for (int i = 0; i < 8; ++i)
#pragma unroll
    for (int j = 0; j < 8; ++j) acc[i][j] = 0.f;

  for (int kc = 0; kc < K; kc += 8) {
    const float4 av = *(const float4*)(A + (size_t)(m0 + arow) * K + kc + apos);
    float4 bv;
    if (!BT) bv = *(const float4*)(B + (size_t)(kc + brow) * N + n0 + bcol);
    else     bv = *(const float4*)(B + (size_t)(n0 + arow) * K + kc + apos);
    __syncthreads();
    as[apos + 0][arow] = av.x;
    as[apos + 1][arow] = av.y;
    as[apos + 2][arow] = av.z;
    as[apos + 3][arow] = av.w;
    if (!BT) {
      *(float4*)&bs[brow][bcol] = bv;
    } else {
      bs[apos + 0][arow] = bv.x;
      bs[apos + 1][arow] = bv.y;
      bs[apos + 2][arow] = bv.z;
      bs[apos + 3][arow] = bv.w;
    }
    __syncthreads();
#pragma unroll
    for (int kk = 0; kk < 8; ++kk) {
      float a[8], b[8];
      *(float4*)&a[0] = *(const float4*)&as[kk][tr];
      *(float4*)&a[4] = *(const float4*)&as[kk][tr + 4];
      *(float4*)&b[0] = *(const float4*)&bs[kk][tc];
      *(float4*)&b[4] = *(const float4*)&bs[kk][tc + 4];
#pragma unroll
      for (int i = 0; i < 8; ++i)
#pragma unroll
        for (int j = 0; j < 8; ++j) acc[i][j] = fmaf(a[i], b[j], acc[i][j]);
    }
  }

#pragma unroll
  for (int i = 0; i < 8; ++i) {
    float4 v0 = {acc[i][0], acc[i][1], acc[i][2], acc[i][3]};
    float4 v1 = {acc[i][4], acc[i][5], acc[i][6], acc[i][7]};
    float* cp = C + (size_t)(m0 + tr + i) * N + n0 + tc;
    *(float4*)cp       = v0;
    *(float4*)(cp + 4) = v1;
  }
}

// ---------------------------------------------------------------------------
// attn_scores: per-batch S = relu(qk_b @ feat_b^T) .* (graph!=0), softmax over
// n (axis=1, masked zeros participate).  512 threads, 16x32 grid, 7x4 microtile.
// ---------------------------------------------------------------------------
__global__ __launch_bounds__(512)
void attn_scores(const float* __restrict__ qk, const float* __restrict__ feat,
                 const int* __restrict__ graph, float* __restrict__ S) {
  __shared__ float s[NOBJ * NOBJ];
  __shared__ float stg[2 * 128 * 17];
  float* qs = stg;
  float* ks = stg + 128 * 17;

  const int b  = blockIdx.x;
  const int t  = threadIdx.x;
  const int tn = t >> 5;    // 0..15
  const int tm = t & 31;    // 0..31

  const float* qb = qk   + (size_t)b * NOBJ * 1024;
  const float* fb = feat + (size_t)b * NOBJ * 1024;

  for (int idx = t; idx < 28 * 17; idx += 512) {   // zero pad rows 100..127
    qs[100 * 17 + idx] = 0.f;
    ks[100 * 17 + idx] = 0.f;
  }

  float acc[7][4];
#pragma unroll
  for (int i = 0; i < 7; ++i)
#pragma unroll
    for (int j = 0; j < 4; ++j) acc[i][j] = 0.f;

  for (int kc = 0; kc < 1024; kc += 16) {
    __syncthreads();
    for (int idx = t; idx < NOBJ * 4; idx += 512) {
      const int n = idx >> 2, c4 = (idx & 3) * 4;
      const float4 qv = *(const float4*)(qb + n * 1024 + kc + c4);
      const float4 kv = *(const float4*)(fb + n * 1024 + kc + c4);
      float* qd = qs + n * 17 + c4;
      float* kd = ks + n * 17 + c4;
      qd[0] = qv.x; qd[1] = qv.y; qd[2] = qv.z; qd[3] = qv.w;
      kd[0] = kv.x; kd[1] = kv.y; kd[2] = kv.z; kd[3] = kv.w;
    }
    __syncthreads();
#pragma unroll 4
    for (int kk = 0; kk < 16; ++kk) {
      float qv[7], kv[4];
#pragma unroll
      for (int i = 0; i < 7; ++i) qv[i] = qs[(tn + 16 * i) * 17 + kk];
#pragma unroll
      for (int j = 0; j < 4; ++j) kv[j] = ks[(tm + 32 * j) * 17 + kk];
#pragma unroll
      for (int i = 0; i < 7; ++i)
#pragma unroll
        for (int j = 0; j < 4; ++j) acc[i][j] = fmaf(qv[i], kv[j], acc[i][j]);
    }
  }

  const int* gb = graph + (size_t)b * NOBJ * NOBJ;
#pragma unroll
  for (int i = 0; i < 7; ++i) {
    const int n = tn + 16 * i;
    if (n >= NOBJ) break;
#pragma unroll
    for (int j = 0; j < 4; ++j) {
      const int m = tm + 32 * j;
      if (m < NOBJ) {
        float v = acc[i][j];
        v = v > 0.f ? v : 0.f;
        s[n * NOBJ + m] = (gb[n * NOBJ + m] != 0) ? v : 0.f;
      }
    }
  }
  __syncthreads();

  if (t < NOBJ) {   // softmax over n for column m=t (values >=0 -> max seed 0)
    const int m = t;
    float mx = 0.f;
    for (int n = 0; n < NOBJ; ++n) mx = fmaxf(mx, s[n * NOBJ + m]);
    float sum = 0.f;
    for (int n = 0; n < NOBJ; ++n) {
      const float e = expf(s[n * NOBJ + m] - mx);
      s[n * NOBJ + m] = e;
      sum += e;
    }
    const float inv = 1.f / sum;
    for (int n = 0; n < NOBJ; ++n) s[n * NOBJ + m] *= inv;
  }
  __syncthreads();

  float* Sb = S + (size_t)b * NOBJ * NOBJ;
  for (int idx = t; idx < NOBJ * NOBJ; idx += 512) Sb[idx] = s[idx];
}

// ---------------------------------------------------------------------------
// attn_agg: out[b,n,oc:oc+64] = sum_m S[b,n,m] * outp[b,m,oc:oc+64]
// grid (16, 256) -> 4096 blocks (16/CU) fixes the 1-block/CU latency problem.
// ---------------------------------------------------------------------------
__global__ __launch_bounds__(256)
void attn_agg(const float* __restrict__ S, const float* __restrict__ outp,
              float* __restrict__ out) {
  __shared__ float s[NOBJ * NOBJ];
  const int b = blockIdx.y, oc = blockIdx.x * 64;
  const int t = threadIdx.x;
  const float4* Sb4 = (const float4*)(S + (size_t)b * NOBJ * NOBJ);
  for (int idx = t; idx < NOBJ * NOBJ / 4; idx += 256) ((float4*)s)[idx] = Sb4[idx];
  __syncthreads();

  const int col = (t & 15) * 4, ng = t >> 4;
  float a[7][4];
#pragma unroll
  for (int i = 0; i < 7; ++i)
#pragma unroll
    for (int j = 0; j < 4; ++j) a[i][j] = 0.f;

  int nrow[7];
#pragma unroll
  for (int i = 0; i < 7; ++i) {
    const int n = ng + 16 * i;
    nrow[i] = (n < NOBJ ? n : 0) * NOBJ;
  }

  const float* ob = outp + (size_t)b * NOBJ * 1024 + oc + col;
  for (int m = 0; m < NOBJ; ++m) {
    const float4 ov = *(const float4*)(ob + (size_t)m * 1024);
#pragma unroll
    for (int i = 0; i < 7; ++i) {
      const float w = s[nrow[i] + m];
      a[i][0] = fmaf(w, ov.x, a[i][0]);
      a[i][1] = fmaf(w, ov.y, a[i][1]);
      a[i][2] = fmaf(w, ov.z, a[i][2]);
      a[i][3] = fmaf(w, ov.w, a[i][3]);
    }
  }

  float* outb = out + (size_t)b * NOBJ * 1024 + oc + col;
#pragma unroll
  for (int i = 0; i < 7; ++i) {
    const int n = ng + 16 * i;
    if (n < NOBJ) {
      float4 r = {a[i][0], a[i][1], a[i][2], a[i][3]};
      *(float4*)(outb + (size_t)n * 1024) = r;
    }
  }
}

// ---------------------------------------------------------------------------
// Fallback attention (round-1, used only if ws too small for new path)
// ---------------------------------------------------------------------------
__global__ __launch_bounds__(256)
void attn_fused(const float* __restrict__ qk, const float* __restrict__ feat,
                const float* __restrict__ outp, const int* __restrict__ graph,
                float* __restrict__ out) {
  __shared__ float s[NOBJ * NOBJ];
  __shared__ float stg[2 * 112 * 17];
  float* qs = stg;
  float* ks = stg + 112 * 17;
  const int b  = blockIdx.x;
  const int t  = threadIdx.x;
  const int tn = t >> 4;
  const int tm = t & 15;
  const float* qb = qk   + (size_t)b * NOBJ * 1024;
  const float* fb = feat + (size_t)b * NOBJ * 1024;
  for (int idx = t; idx < 12 * 17; idx += 256) {
    qs[100 * 17 + idx] = 0.f;
    ks[100 * 17 + idx] = 0.f;
  }
  float acc[7][7];
#pragma unroll
  for (int i = 0; i < 7; ++i)
#pragma unroll
    for (int j = 0; j < 7; ++j) acc[i][j] = 0.f;
  for (int kc = 0; kc < 1024; kc += 16) {
    __syncthreads();
    for (int idx = t; idx < NOBJ * 4; idx += 256) {
      const int n = idx >> 2, c4 = (idx & 3) * 4;
      const float4 qv = *(const float4*)(qb + n * 1024 + kc + c4);
      const float4 kv = *(const float4*)(fb + n * 1024 + kc + c4);
      float* qd = qs + n * 17 + c4;
      float* kd = ks + n * 17 + c4;
      qd[0] = qv.x; qd[1] = qv.y; qd[2] = qv.z; qd[3] = qv.w;
      kd[0] = kv.x; kd[1] = kv.y; kd[2] = kv.z; kd[3] = kv.w;
    }
    __syncthreads();
#pragma unroll 4
    for (int kk = 0; kk < 16; ++kk) {
      float qv[7], kv[7];
#pragma unroll
      for (int i = 0; i < 7; ++i) qv[i] = qs[(tn + 16 * i) * 17 + kk];
#pragma unroll
      for (int j = 0; j < 7; ++j) kv[j] = ks[(tm + 16 * j) * 17 + kk];
#pragma unroll
      for (int i = 0; i < 7; ++i)
#pragma unroll
        for (int j = 0; j < 7; ++j) acc[i][j] = fmaf(qv[i], kv[j], acc[i][j]);
    }
  }
  const int* gb = graph + (size_t)b * NOBJ * NOBJ;
#pragma unroll
  for (int i = 0; i < 7; ++i) {
    const int n = tn + 16 * i;
    if (n >= NOBJ) break;
#pragma unroll
    for (int j = 0; j < 7; ++j) {
      const int m = tm + 16 * j;
      if (m < NOBJ) {
        float v = acc[i][j];
        v = v > 0.f ? v : 0.f;
        s[n * NOBJ + m] = (gb[n * NOBJ + m] != 0) ? v : 0.f;
      }
    }
  }
  __syncthreads();
  if (t < NOBJ) {
    const int m = t;
    float mx = 0.f;
    for (int n = 0; n < NOBJ; ++n) mx = fmaxf(mx, s[n * NOBJ + m]);
    float sum = 0.f;
    for (int n = 0; n < NOBJ; ++n) {
      const float e = expf(s[n * NOBJ + m] - mx);
      s[n * NOBJ + m] = e;
      sum += e;
    }
    const float inv = 1.f / sum;
    for (int n = 0; n < NOBJ; ++n) s[n * NOBJ + m] *= inv;
  }
  __syncthreads();
  const float* ob   = outp + (size_t)b * NOBJ * 1024;
  float*       outb = out  + (size_t)b * NOBJ * 1024;
  int nrow[7];
#pragma unroll
  for (int i = 0; i < 7; ++i) {
    const int n = tn + 16 * i;
    nrow[i] = (n < NOBJ ? n : 0) * NOBJ;
  }
  for (int oc = 0; oc < 1024; oc += 64) {
    float a[7][4];
#pragma unroll
    for (int i = 0; i < 7; ++i)
#pragma unroll
      for (int j = 0; j < 4; ++j) a[i][j] = 0.f;
    for (int m = 0; m < NOBJ; ++m) {
      const float4 ov = *(const float4*)(ob + m * 1024 + oc + tm * 4);
      float w[7];
#pragma unroll
      for (int i = 0; i < 7; ++i) w[i] = s[nrow[i] + m];
#pragma unroll
      for (int i = 0; i < 7; ++i) {
        a[i][0] = fmaf(w[i], ov.x, a[i][0]);
        a[i][1] = fmaf(w[i], ov.y, a[i][1]);
        a[i][2] = fmaf(w[i], ov.z, a[i][2]);
        a[i][3] = fmaf(w[i], ov.w, a[i][3]);
      }
    }
#pragma unroll
    for (int i = 0; i < 7; ++i) {
      const int n = tn + 16 * i;
      if (n < NOBJ) {
        float4 r = {a[i][0], a[i][1], a[i][2], a[i][3]};
        *(float4*)(outb + n * 1024 + oc + tm * 4) = r;
      }
    }
  }
}

// ---------------------------------------------------------------------------
// inputs: feature [256,100,1024] f32 | graph [256,100,100] i32 |
//         weight [1024,1024] | wq [1024,1024] | wk [1024,1024]
// math: out = softmax_n(relu(X (WqWk^T) X^T) .* (G!=0)) @ (X W)
// ws (new path, 228.3 MB): outp f32 | qkb f32 | wthi/lo bf16 | m1thi/lo bf16 | S f32
//   (m1t f32 aliases qkb[0:1M] — consumed before qkb GEMM writes)
// d_out doubles as Xhi/Xlo bf16 staging (written before use, overwritten at end)
// ---------------------------------------------------------------------------
extern "C" void kernel_launch(void* const* d_in, const int* in_sizes, int n_in,
                              void* d_out, int out_size, void* d_ws, size_t ws_size,
                              hipStream_t stream) {
  const float* feature = (const float*)d_in[0];
  const int*   graph   = (const int*)  d_in[1];
  const float* weight  = (const float*)d_in[2];
  const float* wq      = (const float*)d_in[3];
  const float* wk      = (const float*)d_in[4];
  float* out = (float*)d_out;

  const size_t NF = (size_t)25600 * 1024;              // 26,214,400
  const size_t need_new = (NF * 2 + 2560000) * 4 + (size_t)8 * 1048576 * 2;
  const size_t need_old = (NF * 2 + (size_t)1024 * 1024) * 4;
  const dim3 blk(256);

  if (ws_size >= need_new) {
    float* outp = (float*)d_ws;
    float* qkb  = outp + NF;
    unsigned short* wthi  = (unsigned short*)(qkb + NF);
    unsigned short* wtlo  = wthi + 1048576;
    unsigned short* m1thi = wtlo + 1048576;
    unsigned short* m1tlo = m1thi + 1048576;
    float* S    = (float*)(m1tlo + 1048576);
    float* m1t  = qkb;                                  // alias, consumed early
    unsigned short* xhi = (unsigned short*)d_out;       // d_out as bf16 staging
    unsigned short* xlo = xhi + NF;

    split_ew<<<4096, blk, 0, stream>>>(feature, xhi, xlo, (long long)(NF / 8));
    split_tr<<<dim3(32, 32), blk, 0, stream>>>(weight, wthi, wtlo);
    // m1t[j][i] = sum_o wk[j][o] wq[i][o]  (fp32; small & exact)
    gemm128x128<true><<<dim3(8, 8), blk, 0, stream>>>(wk, wq, m1t, 1024, 1024, 1024);
    split_ew<<<512, blk, 0, stream>>>(m1t, m1thi, m1tlo, 1048576 / 8);
    // outp = X @ W
    gemm_mfma3<<<dim3(8, 200), blk, 0, stream>>>(xhi, xlo, wthi, wtlo, outp, 25600, 1024, 1024);
    // qkb = X @ M1   (Bt = m1t)
    gemm_mfma3<<<dim3(8, 200), blk, 0, stream>>>(xhi, xlo, m1thi, m1tlo, qkb, 25600, 1024, 1024);
    attn_scores<<<dim3(256), dim3(512), 0, stream>>>(qkb, feature, graph, S);
    attn_agg<<<dim3(16, 256), blk, 0, stream>>>(S, outp, out);
  } else if (ws_size >= need_old) {
    // fallback: round-1 verified fp32 path
    float* outp = (float*)d_ws;
    float* qkb  = outp + NF;
    float* m1   = qkb + NF;
    gemm128x128<true><<<dim3(8, 8), blk, 0, stream>>>(wq, wk, m1, 1024, 1024, 1024);
    gemm128x128<false><<<dim3(8, 200), blk, 0, stream>>>(feature, weight, outp, 25600, 1024, 1024);
    gemm128x128<false><<<dim3(8, 200), blk, 0, stream>>>(feature, m1, qkb, 25600, 1024, 1024);
    attn_fused<<<dim3(256), blk, 0, stream>>>(qkb, feature, outp, graph, out);
  }
}

// Round 3
// 794.615 us; speedup vs baseline: 2.5305x; 1.2349x over previous
//
#include <hip/hip_runtime.h>
#include <cstdint>
#include <cstddef>

#define NOBJ 100

typedef __attribute__((ext_vector_type(8))) short short8;
typedef __attribute__((ext_vector_type(4))) float f32x4;

typedef const __attribute__((address_space(1))) void* gas_cptr;
typedef __attribute__((address_space(3))) void* las_ptr;

__device__ __forceinline__ void gload_lds16(const void* g, void* l) {
  __builtin_amdgcn_global_load_lds((gas_cptr)g, (las_ptr)l, 16, 0, 0);
}

// ---- bf16 helpers (RTNE via integer trick; finite data only) ----
__device__ __forceinline__ unsigned short bf16_rtne(float x) {
  unsigned u = __builtin_bit_cast(unsigned, x);
  unsigned r = u + 0x7FFFu + ((u >> 16) & 1u);
  return (unsigned short)(r >> 16);
}
__device__ __forceinline__ float bf16_to_f32(unsigned short h) {
  unsigned u = ((unsigned)h) << 16;
  return __builtin_bit_cast(float, u);
}

// ---------------------------------------------------------------------------
// split_ew: f32[n] -> hi bf16[n], lo bf16[n].  n8 = n/8.
// ---------------------------------------------------------------------------
__global__ __launch_bounds__(256)
void split_ew(const float* __restrict__ in, unsigned short* __restrict__ hi,
              unsigned short* __restrict__ lo, long long n8) {
  for (long long u = (long long)blockIdx.x * 256 + threadIdx.x; u < n8;
       u += (long long)gridDim.x * 256) {
    const float4* p = (const float4*)(in + u * 8);
    float4 v0 = p[0], v1 = p[1];
    float x[8] = {v0.x, v0.y, v0.z, v0.w, v1.x, v1.y, v1.z, v1.w};
    unsigned h[8], l[8];
#pragma unroll
    for (int j = 0; j < 8; ++j) {
      h[j] = bf16_rtne(x[j]);
      l[j] = bf16_rtne(x[j] - bf16_to_f32((unsigned short)h[j]));
    }
    uint4 hv, lv;
    hv.x = h[0] | (h[1] << 16); hv.y = h[2] | (h[3] << 16);
    hv.z = h[4] | (h[5] << 16); hv.w = h[6] | (h[7] << 16);
    lv.x = l[0] | (l[1] << 16); lv.y = l[2] | (l[3] << 16);
    lv.z = l[4] | (l[5] << 16); lv.w = l[6] | (l[7] << 16);
    *(uint4*)(hi + u * 8) = hv;
    *(uint4*)(lo + u * 8) = lv;
  }
}

// ---------------------------------------------------------------------------
// split_tr: W f32 [1024][1024] -> Wt hi/lo bf16 [1024][1024] transposed.
// ---------------------------------------------------------------------------
__global__ __launch_bounds__(256)
void split_tr(const float* __restrict__ W, unsigned short* __restrict__ thi,
              unsigned short* __restrict__ tlo) {
  __shared__ float tile[32][33];
  const int r0 = blockIdx.y * 32, c0 = blockIdx.x * 32;
  const int tx = threadIdx.x & 31, ty = threadIdx.x >> 5;
  for (int rr = ty; rr < 32; rr += 8)
    tile[rr][tx] = W[(size_t)(r0 + rr) * 1024 + c0 + tx];
  __syncthreads();
  for (int cc = ty; cc < 32; cc += 8) {
    float x = tile[tx][cc];
    unsigned short h = bf16_rtne(x);
    unsigned short l = bf16_rtne(x - bf16_to_f32(h));
    size_t o = (size_t)(c0 + cc) * 1024 + r0 + tx;
    thi[o] = h;
    tlo[o] = l;
  }
}

// ---------------------------------------------------------------------------
// gemm_mfma3<EPI>: acc = A @ Bt^T via bf16 hi/lo split (3 MFMAs: hh+hl+lh).
// A hi/lo: bf16 [M][K]; Bt hi/lo: bf16 [N][K].
// EPI=0: Ch/Cl bf16 [M][N] row-major (hi and lo of acc)       [qk]
// EPI=1: Ch only, transposed per-batch: Ch[(row/100*1024+col)*128 + row%100]
//        (stride-128 k-padded layout for the agg GEMM; pads left unwritten,
//         neutralized by zeroed A-side k-pad in attn_agg_mfma)      [opT]
// EPI=2: Ch/Cl transposed plain: C[col*1024+row]                    [m1t]
// 128x128 tile, BK=32, 4 waves (2x2), 4x4 16x16x32 frags/wave.
// XOR slot swizzle on staging source + frag read (both-sides, rule 21).
// ---------------------------------------------------------------------------
template<int EPI>
__global__ __launch_bounds__(256)
void gemm_mfma3(const unsigned short* __restrict__ Ah, const unsigned short* __restrict__ Al,
                const unsigned short* __restrict__ Bh, const unsigned short* __restrict__ Bl,
                unsigned short* __restrict__ Ch, unsigned short* __restrict__ Cl,
                int M, int N, int K) {
  __shared__ unsigned short s_ah[4096], s_al[4096], s_bh[4096], s_bl[4096];
  const int t = threadIdx.x;
  const int wid = t >> 6, lane = t & 63;
  const int wr = wid >> 1, wc = wid & 1;
  const int lrow = lane & 15, q = lane >> 4;
  const int m0 = blockIdx.y * 128, n0 = blockIdx.x * 128;

  const int srow = t >> 2;
  const int skch = (t & 3) ^ ((t >> 3) & 3);
  const unsigned short* gAh = Ah + (size_t)(m0 + srow) * K + skch * 8;
  const unsigned short* gAl = Al + (size_t)(m0 + srow) * K + skch * 8;
  const unsigned short* gBh = Bh + (size_t)(n0 + srow) * K + skch * 8;
  const unsigned short* gBl = Bl + (size_t)(n0 + srow) * K + skch * 8;
  const size_t rstep = (size_t)64 * K;
  unsigned short* dA0  = &s_ah[wid * 512];
  unsigned short* dA1  = &s_ah[wid * 512 + 2048];
  unsigned short* dAl0 = &s_al[wid * 512];
  unsigned short* dAl1 = &s_al[wid * 512 + 2048];
  unsigned short* dB0  = &s_bh[wid * 512];
  unsigned short* dB1  = &s_bh[wid * 512 + 2048];
  unsigned short* dBl0 = &s_bl[wid * 512];
  unsigned short* dBl1 = &s_bl[wid * 512 + 2048];

  const int fq = (q ^ ((lrow >> 1) & 3)) * 8;

  f32x4 acc[4][4];
#pragma unroll
  for (int i = 0; i < 4; ++i)
#pragma unroll
    for (int j = 0; j < 4; ++j) acc[i][j] = (f32x4){0.f, 0.f, 0.f, 0.f};

  for (int kc = 0; kc < K; kc += 32) {
    gload_lds16(gAh + kc, dA0);
    gload_lds16(gAh + kc + rstep, dA1);
    gload_lds16(gAl + kc, dAl0);
    gload_lds16(gAl + kc + rstep, dAl1);
    gload_lds16(gBh + kc, dB0);
    gload_lds16(gBh + kc + rstep, dB1);
    gload_lds16(gBl + kc, dBl0);
    gload_lds16(gBl + kc + rstep, dBl1);
    __syncthreads();

    short8 a_h[4], a_l[4];
#pragma unroll
    for (int i = 0; i < 4; ++i) {
      const int ra = (wr * 64 + i * 16 + lrow) * 32 + fq;
      a_h[i] = *(const short8*)&s_ah[ra];
      a_l[i] = *(const short8*)&s_al[ra];
    }
#pragma unroll
    for (int j = 0; j < 4; ++j) {
      const int rb = (wc * 64 + j * 16 + lrow) * 32 + fq;
      short8 b_h = *(const short8*)&s_bh[rb];
      short8 b_l = *(const short8*)&s_bl[rb];
#pragma unroll
      for (int i = 0; i < 4; ++i) {
        acc[i][j] = __builtin_amdgcn_mfma_f32_16x16x32_bf16(a_h[i], b_h, acc[i][j], 0, 0, 0);
        acc[i][j] = __builtin_amdgcn_mfma_f32_16x16x32_bf16(a_h[i], b_l, acc[i][j], 0, 0, 0);
        acc[i][j] = __builtin_amdgcn_mfma_f32_16x16x32_bf16(a_l[i], b_h, acc[i][j], 0, 0, 0);
      }
    }
    __syncthreads();
  }

  // C/D layout (m89-verified): col = lane&15, row = (lane>>4)*4 + reg
#pragma unroll
  for (int i = 0; i < 4; ++i) {
    const int row0 = m0 + wr * 64 + i * 16 + q * 4;
#pragma unroll
    for (int j = 0; j < 4; ++j) {
      const int col = n0 + wc * 64 + j * 16 + lrow;
      unsigned short h[4];
#pragma unroll
      for (int r = 0; r < 4; ++r) h[r] = bf16_rtne(acc[i][j][r]);
      if (EPI == 0) {
#pragma unroll
        for (int r = 0; r < 4; ++r) {
          const size_t o = (size_t)(row0 + r) * N + col;
          Ch[o] = h[r];
          Cl[o] = bf16_rtne(acc[i][j][r] - bf16_to_f32(h[r]));
        }
      } else if (EPI == 1) {
        const unsigned bb = (unsigned)row0 / 100u;       // 4-row group never
        const unsigned ml = (unsigned)row0 - bb * 100u;  // straddles a batch
        uint2 hv;
        hv.x = (unsigned)h[0] | ((unsigned)h[1] << 16);
        hv.y = (unsigned)h[2] | ((unsigned)h[3] << 16);
        *(uint2*)(Ch + ((size_t)bb * 1024 + col) * 128 + ml) = hv;
      } else {
        unsigned short l[4];
#pragma unroll
        for (int r = 0; r < 4; ++r) l[r] = bf16_rtne(acc[i][j][r] - bf16_to_f32(h[r]));
        uint2 hv, lv;
        hv.x = (unsigned)h[0] | ((unsigned)h[1] << 16);
        hv.y = (unsigned)h[2] | ((unsigned)h[3] << 16);
        lv.x = (unsigned)l[0] | ((unsigned)l[1] << 16);
        lv.y = (unsigned)l[2] | ((unsigned)l[3] << 16);
        *(uint2*)(Ch + (size_t)col * 1024 + row0) = hv;
        *(uint2*)(Cl + (size_t)col * 1024 + row0) = lv;
      }
    }
  }
}

// ---------------------------------------------------------------------------
// attn_scores_mfma: per-batch S = relu(qk_b @ X_b^T) .* (graph!=0), softmax
// over n.  128x128-padded MFMA GEMM; pad rows clamp to row 99 on the staging
// *source* side (per-lane global addr; LDS dest stays linear), pad results
// discarded at the epilogue.  Then in-LDS mask/softmax, S f32 out.
// ---------------------------------------------------------------------------
__global__ __launch_bounds__(256)
void attn_scores_mfma(const unsigned short* __restrict__ Qh, const unsigned short* __restrict__ Ql,
                      const unsigned short* __restrict__ Xh, const unsigned short* __restrict__ Xl,
                      const int* __restrict__ graph, float* __restrict__ S) {
  __shared__ unsigned short s_ah[4096], s_al[4096], s_bh[4096], s_bl[4096];
  __shared__ float s[NOBJ * NOBJ];
  const int t = threadIdx.x;
  const int wid = t >> 6, lane = t & 63;
  const int wr = wid >> 1, wc = wid & 1;
  const int lrow = lane & 15, q = lane >> 4;
  const int bb = blockIdx.x;

  const int srow = t >> 2;
  const int skch = (t & 3) ^ ((t >> 3) & 3);
  const int r0c = srow;                                   // 0..63 always valid
  const int r1c = (srow + 64) < NOBJ ? (srow + 64) : (NOBJ - 1);
  const size_t base = (size_t)bb * NOBJ * 1024;
  const unsigned short* gQh0 = Qh + base + (size_t)r0c * 1024 + skch * 8;
  const unsigned short* gQh1 = Qh + base + (size_t)r1c * 1024 + skch * 8;
  const unsigned short* gQl0 = Ql + base + (size_t)r0c * 1024 + skch * 8;
  const unsigned short* gQl1 = Ql + base + (size_t)r1c * 1024 + skch * 8;
  const unsigned short* gXh0 = Xh + base + (size_t)r0c * 1024 + skch * 8;
  const unsigned short* gXh1 = Xh + base + (size_t)r1c * 1024 + skch * 8;
  const unsigned short* gXl0 = Xl + base + (size_t)r0c * 1024 + skch * 8;
  const unsigned short* gXl1 = Xl + base + (size_t)r1c * 1024 + skch * 8;
  unsigned short* dA0  = &s_ah[wid * 512];
  unsigned short* dA1  = &s_ah[wid * 512 + 2048];
  unsigned short* dAl0 = &s_al[wid * 512];
  unsigned short* dAl1 = &s_al[wid * 512 + 2048];
  unsigned short* dB0  = &s_bh[wid * 512];
  unsigned short* dB1  = &s_bh[wid * 512 + 2048];
  unsigned short* dBl0 = &s_bl[wid * 512];
  unsigned short* dBl1 = &s_bl[wid * 512 + 2048];

  const int fq = (q ^ ((lrow >> 1) & 3)) * 8;

  f32x4 acc[4][4];
#pragma unroll
  for (int i = 0; i < 4; ++i)
#pragma unroll
    for (int j = 0; j < 4; ++j) acc[i][j] = (f32x4){0.f, 0.f, 0.f, 0.f};

  for (int kc = 0; kc < 1024; kc += 32) {
    gload_lds16(gQh0 + kc, dA0);
    gload_lds16(gQh1 + kc, dA1);
    gload_lds16(gQl0 + kc, dAl0);
    gload_lds16(gQl1 + kc, dAl1);
    gload_lds16(gXh0 + kc, dB0);
    gload_lds16(gXh1 + kc, dB1);
    gload_lds16(gXl0 + kc, dBl0);
    gload_lds16(gXl1 + kc, dBl1);
    __syncthreads();

    short8 a_h[4], a_l[4];
#pragma unroll
    for (int i = 0; i < 4; ++i) {
      const int ra = (wr * 64 + i * 16 + lrow) * 32 + fq;
      a_h[i] = *(const short8*)&s_ah[ra];
      a_l[i] = *(const short8*)&s_al[ra];
    }
#pragma unroll
    for (int j = 0; j < 4; ++j) {
      const int rb = (wc * 64 + j * 16 + lrow) * 32 + fq;
      short8 b_h = *(const short8*)&s_bh[rb];
      short8 b_l = *(const short8*)&s_bl[rb];
#pragma unroll
      for (int i = 0; i < 4; ++i) {
        acc[i][j] = __builtin_amdgcn_mfma_f32_16x16x32_bf16(a_h[i], b_h, acc[i][j], 0, 0, 0);
        acc[i][j] = __builtin_amdgcn_mfma_f32_16x16x32_bf16(a_h[i], b_l, acc[i][j], 0, 0, 0);
        acc[i][j] = __builtin_amdgcn_mfma_f32_16x16x32_bf16(a_l[i], b_h, acc[i][j], 0, 0, 0);
      }
    }
    __syncthreads();
  }

  // relu + adjacency mask -> s (valid region only)
  const int* gb = graph + (size_t)bb * NOBJ * NOBJ;
#pragma unroll
  for (int i = 0; i < 4; ++i) {
    const int row0 = wr * 64 + i * 16 + q * 4;
#pragma unroll
    for (int j = 0; j < 4; ++j) {
      const int col = wc * 64 + j * 16 + lrow;
      if (col < NOBJ) {
#pragma unroll
        for (int r = 0; r < 4; ++r) {
          const int n = row0 + r;
          if (n < NOBJ) {
            float v = acc[i][j][r];
            v = v > 0.f ? v : 0.f;
            s[n * NOBJ + col] = (gb[n * NOBJ + col] != 0) ? v : 0.f;
          }
        }
      }
    }
  }
  __syncthreads();

  if (t < NOBJ) {   // softmax over n for column m=t (values >=0 -> max seed 0)
    const int m = t;
    float mx = 0.f;
    for (int n = 0; n < NOBJ; ++n) mx = fmaxf(mx, s[n * NOBJ + m]);
    float sum = 0.f;
    for (int n = 0; n < NOBJ; ++n) {
      const float e = expf(s[n * NOBJ + m] - mx);
      s[n * NOBJ + m] = e;
      sum += e;
    }
    const float inv = 1.f / sum;
    for (int n = 0; n < NOBJ; ++n) s[n * NOBJ + m] *= inv;
  }
  __syncthreads();

  float* Sb = S + (size_t)bb * NOBJ * NOBJ;
  for (int idx = t; idx < NOBJ * NOBJ; idx += 256) Sb[idx] = s[idx];
}

// ---------------------------------------------------------------------------
// attn_agg_mfma: out[b,n,:] = sum_m S~[n][m] * outp[m,:] via MFMA.
// A = S hi/lo (f32->split in LDS, XOR-swizzled, k-pad zeroed), K=128.
// B = opT rows (b*1024+o), staged via gload_lds with pre-swizzled source.
// Zeroed A k-pad (m=100..127) annihilates opT's unwritten pad columns.
// Grid (16, 256): o-chunk 64 x batch.  LDS 80 KB -> 2 blocks/CU.
// ---------------------------------------------------------------------------
__global__ __launch_bounds__(256)
void attn_agg_mfma(const float* __restrict__ S, const unsigned short* __restrict__ opT,
                   float* __restrict__ out) {
  __shared__ unsigned short shi[128 * 128];
  __shared__ unsigned short slo[128 * 128];
  __shared__ unsigned short bt[64 * 128];
  const int t = threadIdx.x;
  const int wid = t >> 6, lane = t & 63;
  const int wr = wid >> 1, wc = wid & 1;
  const int lrow = lane & 15, q = lane >> 4;
  const int bb = blockIdx.y, o0 = blockIdx.x * 64;

  // stage bt (64 rows x 128 k), source slot pre-swizzled: s' = s ^ (row&7)
#pragma unroll
  for (int p = 0; p < 4; ++p) {
    const int u = p * 256 + t;
    const int row = u >> 4, sl = u & 15;
    const int sp = sl ^ (row & 7);
    gload_lds16(opT + ((size_t)(bb * 1024 + o0 + row)) * 128 + sp * 8,
                bt + (p * 256 + wid * 64) * 8);
  }

  // zero shi/slo (pads must be true zeros)
  {
    unsigned* z1 = (unsigned*)shi;
    unsigned* z2 = (unsigned*)slo;
    for (int idx = t; idx < 8192; idx += 256) { z1[idx] = 0u; z2[idx] = 0u; }
  }
  __syncthreads();

  // S f32 -> hi/lo into swizzled LDS (8B runs stay inside one 16B slot)
  const float* Sb = S + (size_t)bb * NOBJ * NOBJ;
  for (int idx = t; idx < NOBJ * NOBJ / 4; idx += 256) {
    const float4 v = ((const float4*)Sb)[idx];
    const int lin = idx * 4, n = lin / NOBJ, m = lin - n * NOBJ;
    const float x[4] = {v.x, v.y, v.z, v.w};
    unsigned short h[4], l[4];
#pragma unroll
    for (int e = 0; e < 4; ++e) {
      h[e] = bf16_rtne(x[e]);
      l[e] = bf16_rtne(x[e] - bf16_to_f32(h[e]));
    }
    const int byte = ((n * 128 + m) * 2) ^ ((n & 7) << 4);
    uint2 hv, lv;
    hv.x = (unsigned)h[0] | ((unsigned)h[1] << 16);
    hv.y = (unsigned)h[2] | ((unsigned)h[3] << 16);
    lv.x = (unsigned)l[0] | ((unsigned)l[1] << 16);
    lv.y = (unsigned)l[2] | ((unsigned)l[3] << 16);
    *(uint2*)((char*)shi + byte) = hv;
    *(uint2*)((char*)slo + byte) = lv;
  }
  __syncthreads();

  f32x4 acc[4][2];
#pragma unroll
  for (int i = 0; i < 4; ++i)
#pragma unroll
    for (int j = 0; j < 2; ++j) acc[i][j] = (f32x4){0.f, 0.f, 0.f, 0.f};

#pragma unroll
  for (int ks = 0; ks < 4; ++ks) {
    short8 ah[4], al[4], bv[2];
#pragma unroll
    for (int i = 0; i < 4; ++i) {
      const int row = wr * 64 + i * 16 + lrow;
      const int byte = row * 256 + (((ks * 4 + q) ^ (row & 7)) * 16);
      ah[i] = *(const short8*)((char*)shi + byte);
      al[i] = *(const short8*)((char*)slo + byte);
    }
#pragma unroll
    for (int j = 0; j < 2; ++j) {
      const int brow = wc * 32 + j * 16 + lrow;
      const int byte = brow * 256 + (((ks * 4 + q) ^ (brow & 7)) * 16);
      bv[j] = *(const short8*)((char*)bt + byte);
    }
#pragma unroll
    for (int i = 0; i < 4; ++i)
#pragma unroll
      for (int j = 0; j < 2; ++j) {
        acc[i][j] = __builtin_amdgcn_mfma_f32_16x16x32_bf16(ah[i], bv[j], acc[i][j], 0, 0, 0);
        acc[i][j] = __builtin_amdgcn_mfma_f32_16x16x32_bf16(al[i], bv[j], acc[i][j], 0, 0, 0);
      }
  }

#pragma unroll
  for (int i = 0; i < 4; ++i) {
    const int row0 = wr * 64 + i * 16 + q * 4;
#pragma unroll
    for (int j = 0; j < 2; ++j) {
      const int col = o0 + wc * 32 + j * 16 + lrow;
#pragma unroll
      for (int r = 0; r < 4; ++r) {
        const int n = row0 + r;
        if (n < NOBJ)
          out[((size_t)bb * NOBJ + n) * 1024 + col] = acc[i][j][r];
      }
    }
  }
}

// ---------------------------------------------------------------------------
// math: out = softmax_n(relu(X (WqWk^T) X^T) .* (G!=0)) @ (X W)
// inputs: feature [256,100,1024] f32 | graph [256,100,100] i32 |
//         weight | wq | wk [1024,1024] f32
// ws (199 MB): qkhi qklo | opT | wthi wtlo | m1thi m1tlo | wqhi wqlo wkhi wklo | S
// d_out doubles as X hi/lo bf16 staging (dead before attn_agg_mfma writes it).
// ---------------------------------------------------------------------------
extern "C" void kernel_launch(void* const* d_in, const int* in_sizes, int n_in,
                              void* d_out, int out_size, void* d_ws, size_t ws_size,
                              hipStream_t stream) {
  const float* feature = (const float*)d_in[0];
  const int*   graph   = (const int*)  d_in[1];
  const float* weight  = (const float*)d_in[2];
  const float* wq      = (const float*)d_in[3];
  const float* wk      = (const float*)d_in[4];
  float* out = (float*)d_out;

  const size_t NF = (size_t)25600 * 1024;          // 26,214,400
  const size_t OPT = (size_t)256 * 1024 * 128;     // 33,554,432
  const size_t W1 = (size_t)1024 * 1024;           // 1,048,576
  const size_t need = (2 * NF + OPT + 8 * W1) * 2 + (size_t)2560000 * 4;
  if (ws_size < need) return;                      // fail loudly

  unsigned short* qkhi  = (unsigned short*)d_ws;
  unsigned short* qklo  = qkhi + NF;
  unsigned short* opT   = qklo + NF;
  unsigned short* wthi  = opT + OPT;
  unsigned short* wtlo  = wthi + W1;
  unsigned short* m1thi = wtlo + W1;
  unsigned short* m1tlo = m1thi + W1;
  unsigned short* wqhi  = m1tlo + W1;
  unsigned short* wqlo  = wqhi + W1;
  unsigned short* wkhi  = wqlo + W1;
  unsigned short* wklo  = wkhi + W1;
  float* S = (float*)(wklo + W1);
  unsigned short* xhi = (unsigned short*)d_out;    // d_out as bf16 staging
  unsigned short* xlo = xhi + NF;

  const dim3 blk(256);
  split_ew<<<4096, blk, 0, stream>>>(feature, xhi, xlo, (long long)(NF / 8));
  split_ew<<<512, blk, 0, stream>>>(wq, wqhi, wqlo, (long long)(W1 / 8));
  split_ew<<<512, blk, 0, stream>>>(wk, wkhi, wklo, (long long)(W1 / 8));
  split_tr<<<dim3(32, 32), blk, 0, stream>>>(weight, wthi, wtlo);
  // m1t[n][k] = M1[k][n],  M1 = Wq @ Wk^T  (EPI=2: transposed hi/lo store)
  gemm_mfma3<2><<<dim3(8, 8), blk, 0, stream>>>(wqhi, wqlo, wkhi, wklo,
                                                m1thi, m1tlo, 1024, 1024, 1024);
  // opT[(b*1024+o)*128 + m] = (X @ W)[b*100+m][o]  (EPI=1: hi only)
  gemm_mfma3<1><<<dim3(8, 200), blk, 0, stream>>>(xhi, xlo, wthi, wtlo,
                                                  opT, nullptr, 25600, 1024, 1024);
  // qk = X @ M1 (EPI=0: hi/lo row-major)
  gemm_mfma3<0><<<dim3(8, 200), blk, 0, stream>>>(xhi, xlo, m1thi, m1tlo,
                                                  qkhi, qklo, 25600, 1024, 1024);
  attn_scores_mfma<<<dim3(256), blk, 0, stream>>>(qkhi, qklo, xhi, xlo, graph, S);
  attn_agg_mfma<<<dim3(16, 256), blk, 0, stream>>>(S, opT, out);
}

// Round 8
// 745.971 us; speedup vs baseline: 2.6955x; 1.0652x over previous
//
#include <hip/hip_runtime.h>
#include <cstdint>
#include <cstddef>

#define NOBJ 100

typedef __attribute__((ext_vector_type(8))) _Float16 half8;
typedef __attribute__((ext_vector_type(4))) float f32x4;

typedef const __attribute__((address_space(1))) void* gas_cptr;
typedef __attribute__((address_space(3))) void* las_ptr;

__device__ __forceinline__ void gload_lds16(const void* g, void* l) {
  __builtin_amdgcn_global_load_lds((gas_cptr)g, (las_ptr)l, 16, 0, 0);
}

// ---- fp16 split helpers: x = hi + lo, each fp16 (22-bit combined mantissa) ----
__device__ __forceinline__ unsigned short f16h(float x) {
  return __builtin_bit_cast(unsigned short, (_Float16)x);
}
__device__ __forceinline__ void f16split(float x, unsigned& h, unsigned& l) {
  _Float16 hh = (_Float16)x;
  _Float16 ll = (_Float16)(x - (float)hh);
  h = (unsigned)__builtin_bit_cast(unsigned short, hh);
  l = (unsigned)__builtin_bit_cast(unsigned short, ll);
}

// ---------------------------------------------------------------------------
// split_ew: f32[n] -> hi fp16[n], lo fp16[n].  n8 = n/8.
// ---------------------------------------------------------------------------
__global__ __launch_bounds__(256)
void split_ew(const float* __restrict__ in, unsigned short* __restrict__ hi,
              unsigned short* __restrict__ lo, long long n8) {
  for (long long u = (long long)blockIdx.x * 256 + threadIdx.x; u < n8;
       u += (long long)gridDim.x * 256) {
    const float4* p = (const float4*)(in + u * 8);
    float4 v0 = p[0], v1 = p[1];
    float x[8] = {v0.x, v0.y, v0.z, v0.w, v1.x, v1.y, v1.z, v1.w};
    unsigned h[8], l[8];
#pragma unroll
    for (int j = 0; j < 8; ++j) f16split(x[j], h[j], l[j]);
    uint4 hv, lv;
    hv.x = h[0] | (h[1] << 16); hv.y = h[2] | (h[3] << 16);
    hv.z = h[4] | (h[5] << 16); hv.w = h[6] | (h[7] << 16);
    lv.x = l[0] | (l[1] << 16); lv.y = l[2] | (l[3] << 16);
    lv.z = l[4] | (l[5] << 16); lv.w = l[6] | (l[7] << 16);
    *(uint4*)(hi + u * 8) = hv;
    *(uint4*)(lo + u * 8) = lv;
  }
}

// ---------------------------------------------------------------------------
// split_tr: W f32 [1024][1024] -> Wt hi/lo fp16 [1024][1024] transposed.
// ---------------------------------------------------------------------------
__global__ __launch_bounds__(256)
void split_tr(const float* __restrict__ W, unsigned short* __restrict__ thi,
              unsigned short* __restrict__ tlo) {
  __shared__ float tile[32][33];
  const int r0 = blockIdx.y * 32, c0 = blockIdx.x * 32;
  const int tx = threadIdx.x & 31, ty = threadIdx.x >> 5;
  for (int rr = ty; rr < 32; rr += 8)
    tile[rr][tx] = W[(size_t)(r0 + rr) * 1024 + c0 + tx];
  __syncthreads();
  for (int cc = ty; cc < 32; cc += 8) {
    float x = tile[tx][cc];
    unsigned h, l;
    f16split(x, h, l);
    size_t o = (size_t)(c0 + cc) * 1024 + r0 + tx;
    thi[o] = (unsigned short)h;
    tlo[o] = (unsigned short)l;
  }
}

// ---------------------------------------------------------------------------
// gemm_m1: m1t[n][k] = M1[k][n],  M1 = Wq @ Wk^T, fp16 hi/lo 3-MFMA.
// A = wq splits [1024][1024], B = wk splits [1024][1024]. Grid (8,8).
// ---------------------------------------------------------------------------
__global__ __launch_bounds__(256)
void gemm_m1(const unsigned short* __restrict__ Ah, const unsigned short* __restrict__ Al,
             const unsigned short* __restrict__ Bh, const unsigned short* __restrict__ Bl,
             unsigned short* __restrict__ Th, unsigned short* __restrict__ Tl) {
  __shared__ unsigned short s_ah[4096], s_al[4096], s_bh[4096], s_bl[4096];
  const int t = threadIdx.x;
  const int wid = t >> 6, lane = t & 63;
  const int wr = wid >> 1, wc = wid & 1;
  const int lrow = lane & 15, q = lane >> 4;
  const int m0 = blockIdx.y * 128, n0 = blockIdx.x * 128;

  const int srow = t >> 2;
  const int skch = (t & 3) ^ ((t >> 3) & 3);
  const unsigned short* gAh = Ah + (size_t)(m0 + srow) * 1024 + skch * 8;
  const unsigned short* gAl = Al + (size_t)(m0 + srow) * 1024 + skch * 8;
  const unsigned short* gBh = Bh + (size_t)(n0 + srow) * 1024 + skch * 8;
  const unsigned short* gBl = Bl + (size_t)(n0 + srow) * 1024 + skch * 8;
  const size_t rstep = (size_t)64 * 1024;
  unsigned short* dA0  = &s_ah[wid * 512];
  unsigned short* dA1  = &s_ah[wid * 512 + 2048];
  unsigned short* dAl0 = &s_al[wid * 512];
  unsigned short* dAl1 = &s_al[wid * 512 + 2048];
  unsigned short* dB0  = &s_bh[wid * 512];
  unsigned short* dB1  = &s_bh[wid * 512 + 2048];
  unsigned short* dBl0 = &s_bl[wid * 512];
  unsigned short* dBl1 = &s_bl[wid * 512 + 2048];
  const int fq = (q ^ ((lrow >> 1) & 3)) * 8;

  f32x4 acc[4][4];
#pragma unroll
  for (int i = 0; i < 4; ++i)
#pragma unroll
    for (int j = 0; j < 4; ++j) acc[i][j] = (f32x4){0.f, 0.f, 0.f, 0.f};

  for (int kc = 0; kc < 1024; kc += 32) {
    gload_lds16(gAh + kc, dA0);
    gload_lds16(gAh + kc + rstep, dA1);
    gload_lds16(gAl + kc, dAl0);
    gload_lds16(gAl + kc + rstep, dAl1);
    gload_lds16(gBh + kc, dB0);
    gload_lds16(gBh + kc + rstep, dB1);
    gload_lds16(gBl + kc, dBl0);
    gload_lds16(gBl + kc + rstep, dBl1);
    __syncthreads();
    half8 a_h[4], a_l[4];
#pragma unroll
    for (int i = 0; i < 4; ++i) {
      const int ra = (wr * 64 + i * 16 + lrow) * 32 + fq;
      a_h[i] = *(const half8*)&s_ah[ra];
      a_l[i] = *(const half8*)&s_al[ra];
    }
#pragma unroll
    for (int j = 0; j < 4; ++j) {
      const int rb = (wc * 64 + j * 16 + lrow) * 32 + fq;
      half8 b_h = *(const half8*)&s_bh[rb];
      half8 b_l = *(const half8*)&s_bl[rb];
#pragma unroll
      for (int i = 0; i < 4; ++i) {
        acc[i][j] = __builtin_amdgcn_mfma_f32_16x16x32_f16(a_h[i], b_h, acc[i][j], 0, 0, 0);
        acc[i][j] = __builtin_amdgcn_mfma_f32_16x16x32_f16(a_h[i], b_l, acc[i][j], 0, 0, 0);
        acc[i][j] = __builtin_amdgcn_mfma_f32_16x16x32_f16(a_l[i], b_h, acc[i][j], 0, 0, 0);
      }
    }
    __syncthreads();
  }

  // C/D layout: col = lane&15, row = (lane>>4)*4 + reg; store transposed hi/lo
#pragma unroll
  for (int i = 0; i < 4; ++i) {
    const int row0 = m0 + wr * 64 + i * 16 + q * 4;
#pragma unroll
    for (int j = 0; j < 4; ++j) {
      const int col = n0 + wc * 64 + j * 16 + lrow;
      unsigned h[4], l[4];
#pragma unroll
      for (int r = 0; r < 4; ++r) f16split(acc[i][j][r], h[r], l[r]);
      uint2 hv, lv;
      hv.x = h[0] | (h[1] << 16); hv.y = h[2] | (h[3] << 16);
      lv.x = l[0] | (l[1] << 16); lv.y = l[2] | (l[3] << 16);
      *(uint2*)(Th + (size_t)col * 1024 + row0) = hv;
      *(uint2*)(Tl + (size_t)col * 1024 + row0) = lv;
    }
  }
}

// ---------------------------------------------------------------------------
// proj_gemm: BOTH projections in one launch, XCD-swizzled.
//   wgid = (bid%8)*400 + bid/8; row-panel = wgid/16; col-block = wgid%16.
//   col-block < 8:  C = X @ W   -> opT[(b*1024+o)*128 + m]  (fp16 hi only)
//   col-block >= 8: C = X @ M1  -> qk hi/lo row-major [25600][1024]
// All 16 col-blocks of one A panel land on ONE XCD -> A fetched once.
// 128x128 tile, BK=32, fp16 hi/lo 3-MFMA, XOR slot swizzle both sides.
// ---------------------------------------------------------------------------
__global__ __launch_bounds__(256)
void proj_gemm(const unsigned short* __restrict__ Ah, const unsigned short* __restrict__ Al,
               const unsigned short* __restrict__ Wh, const unsigned short* __restrict__ Wl,
               const unsigned short* __restrict__ Mh, const unsigned short* __restrict__ Ml,
               unsigned short* __restrict__ opT, unsigned short* __restrict__ qkh,
               unsigned short* __restrict__ qkl) {
  __shared__ unsigned short s_ah[4096], s_al[4096], s_bh[4096], s_bl[4096];
  const int t = threadIdx.x;
  const int wid = t >> 6, lane = t & 63;
  const int wr = wid >> 1, wc = wid & 1;
  const int lrow = lane & 15, q = lane >> 4;

  const int bid  = blockIdx.x;
  const int wgid = (bid & 7) * 400 + (bid >> 3);   // bijective: 3200 % 8 == 0
  const int m0   = (wgid >> 4) * 128;
  const int cb   = wgid & 15;
  const bool isW = cb < 8;
  const int n0   = (isW ? cb : cb - 8) * 128;
  const unsigned short* Bh = isW ? Wh : Mh;
  const unsigned short* Bl = isW ? Wl : Ml;

  const int srow = t >> 2;
  const int skch = (t & 3) ^ ((t >> 3) & 3);
  const unsigned short* gAh = Ah + (size_t)(m0 + srow) * 1024 + skch * 8;
  const unsigned short* gAl = Al + (size_t)(m0 + srow) * 1024 + skch * 8;
  const unsigned short* gBh = Bh + (size_t)(n0 + srow) * 1024 + skch * 8;
  const unsigned short* gBl = Bl + (size_t)(n0 + srow) * 1024 + skch * 8;
  const size_t rstep = (size_t)64 * 1024;
  unsigned short* dA0  = &s_ah[wid * 512];
  unsigned short* dA1  = &s_ah[wid * 512 + 2048];
  unsigned short* dAl0 = &s_al[wid * 512];
  unsigned short* dAl1 = &s_al[wid * 512 + 2048];
  unsigned short* dB0  = &s_bh[wid * 512];
  unsigned short* dB1  = &s_bh[wid * 512 + 2048];
  unsigned short* dBl0 = &s_bl[wid * 512];
  unsigned short* dBl1 = &s_bl[wid * 512 + 2048];
  const int fq = (q ^ ((lrow >> 1) & 3)) * 8;

  f32x4 acc[4][4];
#pragma unroll
  for (int i = 0; i < 4; ++i)
#pragma unroll
    for (int j = 0; j < 4; ++j) acc[i][j] = (f32x4){0.f, 0.f, 0.f, 0.f};

  for (int kc = 0; kc < 1024; kc += 32) {
    gload_lds16(gAh + kc, dA0);
    gload_lds16(gAh + kc + rstep, dA1);
    gload_lds16(gAl + kc, dAl0);
    gload_lds16(gAl + kc + rstep, dAl1);
    gload_lds16(gBh + kc, dB0);
    gload_lds16(gBh + kc + rstep, dB1);
    gload_lds16(gBl + kc, dBl0);
    gload_lds16(gBl + kc + rstep, dBl1);
    __syncthreads();
    half8 a_h[4], a_l[4];
#pragma unroll
    for (int i = 0; i < 4; ++i) {
      const int ra = (wr * 64 + i * 16 + lrow) * 32 + fq;
      a_h[i] = *(const half8*)&s_ah[ra];
      a_l[i] = *(const half8*)&s_al[ra];
    }
#pragma unroll
    for (int j = 0; j < 4; ++j) {
      const int rb = (wc * 64 + j * 16 + lrow) * 32 + fq;
      half8 b_h = *(const half8*)&s_bh[rb];
      half8 b_l = *(const half8*)&s_bl[rb];
#pragma unroll
      for (int i = 0; i < 4; ++i) {
        acc[i][j] = __builtin_amdgcn_mfma_f32_16x16x32_f16(a_h[i], b_h, acc[i][j], 0, 0, 0);
        acc[i][j] = __builtin_amdgcn_mfma_f32_16x16x32_f16(a_h[i], b_l, acc[i][j], 0, 0, 0);
        acc[i][j] = __builtin_amdgcn_mfma_f32_16x16x32_f16(a_l[i], b_h, acc[i][j], 0, 0, 0);
      }
    }
    __syncthreads();
  }

#pragma unroll
  for (int i = 0; i < 4; ++i) {
    const int row0 = m0 + wr * 64 + i * 16 + q * 4;   // mult of 4; 100%4==0 ->
#pragma unroll                                        // never straddles batch
    for (int j = 0; j < 4; ++j) {
      const int col = n0 + wc * 64 + j * 16 + lrow;
      if (isW) {
        unsigned h[4];
#pragma unroll
        for (int r = 0; r < 4; ++r) h[r] = (unsigned)f16h(acc[i][j][r]);
        const unsigned bb = (unsigned)row0 / 100u;
        const unsigned ml = (unsigned)row0 - bb * 100u;
        uint2 hv;
        hv.x = h[0] | (h[1] << 16);
        hv.y = h[2] | (h[3] << 16);
        *(uint2*)(opT + ((size_t)bb * 1024 + col) * 128 + ml) = hv;
      } else {
        unsigned h[4], l[4];
#pragma unroll
        for (int r = 0; r < 4; ++r) f16split(acc[i][j][r], h[r], l[r]);
#pragma unroll
        for (int r = 0; r < 4; ++r) {
          const size_t o = (size_t)(row0 + r) * 1024 + col;
          qkh[o] = (unsigned short)h[r];
          qkl[o] = (unsigned short)l[r];
        }
      }
    }
  }
}

// ---------------------------------------------------------------------------
// attn_scores_mfma: per-batch S = relu(qk_b @ X_b^T) .* (graph!=0), softmax
// over n (masked zeros participate).  512 threads / 8 waves (2x4), per-wave
// 64x32 tile, fp16 hi/lo 3-MFMA, K=1024 in BK=32 steps.  Pad rows (100..127)
// clamp to row 99 on the per-lane *source* address; results discarded.
// LDS: 4x8KB staging + 40KB scores = 72.7 KB.
// ---------------------------------------------------------------------------
__global__ __launch_bounds__(512)
void attn_scores_mfma(const unsigned short* __restrict__ Qh, const unsigned short* __restrict__ Ql,
                      const unsigned short* __restrict__ Xh, const unsigned short* __restrict__ Xl,
                      const int* __restrict__ graph, float* __restrict__ S) {
  __shared__ unsigned short s_ah[4096], s_al[4096], s_bh[4096], s_bl[4096];
  __shared__ float s[NOBJ * NOBJ];
  const int t = threadIdx.x;
  const int wid = t >> 6, lane = t & 63;
  const int wr = wid >> 2, wc = wid & 3;
  const int lrow = lane & 15, q = lane >> 4;
  const int bb = blockIdx.x;

  const int srow = t >> 2;                         // 0..127
  const int rc   = srow < NOBJ ? srow : (NOBJ - 1);
  const int skch = (t & 3) ^ ((t >> 3) & 3);
  const size_t base = (size_t)bb * NOBJ * 1024;
  const unsigned short* gQh = Qh + base + (size_t)rc * 1024 + skch * 8;
  const unsigned short* gQl = Ql + base + (size_t)rc * 1024 + skch * 8;
  const unsigned short* gXh = Xh + base + (size_t)rc * 1024 + skch * 8;
  const unsigned short* gXl = Xl + base + (size_t)rc * 1024 + skch * 8;
  unsigned short* dQh = &s_ah[wid * 512];          // wave-uniform bases
  unsigned short* dQl = &s_al[wid * 512];
  unsigned short* dXh = &s_bh[wid * 512];
  unsigned short* dXl = &s_bl[wid * 512];
  const int fq = (q ^ ((lrow >> 1) & 3)) * 8;

  f32x4 acc[4][2];
#pragma unroll
  for (int i = 0; i < 4; ++i)
#pragma unroll
    for (int j = 0; j < 2; ++j) acc[i][j] = (f32x4){0.f, 0.f, 0.f, 0.f};

  for (int kc = 0; kc < 1024; kc += 32) {
    gload_lds16(gQh + kc, dQh);
    gload_lds16(gQl + kc, dQl);
    gload_lds16(gXh + kc, dXh);
    gload_lds16(gXl + kc, dXl);
    __syncthreads();
    half8 a_h[4], a_l[4];
#pragma unroll
    for (int i = 0; i < 4; ++i) {
      const int ra = (wr * 64 + i * 16 + lrow) * 32 + fq;
      a_h[i] = *(const half8*)&s_ah[ra];
      a_l[i] = *(const half8*)&s_al[ra];
    }
#pragma unroll
    for (int j = 0; j < 2; ++j) {
      const int rb = (wc * 32 + j * 16 + lrow) * 32 + fq;
      half8 b_h = *(const half8*)&s_bh[rb];
      half8 b_l = *(const half8*)&s_bl[rb];
#pragma unroll
      for (int i = 0; i < 4; ++i) {
        acc[i][j] = __builtin_amdgcn_mfma_f32_16x16x32_f16(a_h[i], b_h, acc[i][j], 0, 0, 0);
        acc[i][j] = __builtin_amdgcn_mfma_f32_16x16x32_f16(a_h[i], b_l, acc[i][j], 0, 0, 0);
        acc[i][j] = __builtin_amdgcn_mfma_f32_16x16x32_f16(a_l[i], b_h, acc[i][j], 0, 0, 0);
      }
    }
    __syncthreads();
  }

  // relu + adjacency mask -> s (valid region only)
  const int* gb = graph + (size_t)bb * NOBJ * NOBJ;
#pragma unroll
  for (int i = 0; i < 4; ++i) {
    const int row0 = wr * 64 + i * 16 + q * 4;
#pragma unroll
    for (int j = 0; j < 2; ++j) {
      const int col = wc * 32 + j * 16 + lrow;
      if (col < NOBJ) {
#pragma unroll
        for (int r = 0; r < 4; ++r) {
          const int n = row0 + r;
          if (n < NOBJ) {
            float v = acc[i][j][r];
            v = v > 0.f ? v : 0.f;
            s[n * NOBJ + col] = (gb[n * NOBJ + col] != 0) ? v : 0.f;
          }
        }
      }
    }
  }
  __syncthreads();

  if (t < NOBJ) {   // softmax over n for column m=t (values >=0 -> max seed 0)
    const int m = t;
    float mx = 0.f;
    for (int n = 0; n < NOBJ; ++n) mx = fmaxf(mx, s[n * NOBJ + m]);
    float sum = 0.f;
    for (int n = 0; n < NOBJ; ++n) {
      const float e = expf(s[n * NOBJ + m] - mx);
      s[n * NOBJ + m] = e;
      sum += e;
    }
    const float inv = 1.f / sum;
    for (int n = 0; n < NOBJ; ++n) s[n * NOBJ + m] *= inv;
  }
  __syncthreads();

  float* Sb = S + (size_t)bb * NOBJ * NOBJ;
  for (int idx = t; idx < NOBJ * NOBJ; idx += 512) Sb[idx] = s[idx];
}

// ---------------------------------------------------------------------------
// attn_agg_mfma: out[b,n,:] = sum_m S~[n][m] * outp[m,:] via fp16 MFMA.
// A = S hi/lo (f32->split in LDS, XOR-swizzled, k-pad m=100..127 ZEROED,
// which annihilates opT's unwritten pad columns).  B = opT rows, staged via
// gload_lds with pre-swizzled source.  Grid (16, 256): o-chunk 64 x batch.
// ---------------------------------------------------------------------------
__global__ __launch_bounds__(256)
void attn_agg_mfma(const float* __restrict__ S, const unsigned short* __restrict__ opT,
                   float* __restrict__ out) {
  __shared__ unsigned short shi[128 * 128];
  __shared__ unsigned short slo[128 * 128];
  __shared__ unsigned short bt[64 * 128];
  const int t = threadIdx.x;
  const int wid = t >> 6, lane = t & 63;
  const int wr = wid >> 1, wc = wid & 1;
  const int lrow = lane & 15, q = lane >> 4;
  const int bb = blockIdx.y, o0 = blockIdx.x * 64;

#pragma unroll
  for (int p = 0; p < 4; ++p) {
    const int u = p * 256 + t;
    const int row = u >> 4, sl = u & 15;
    const int sp = sl ^ (row & 7);
    gload_lds16(opT + ((size_t)(bb * 1024 + o0 + row)) * 128 + sp * 8,
                bt + (p * 256 + wid * 64) * 8);
  }

  {
    unsigned* z1 = (unsigned*)shi;
    unsigned* z2 = (unsigned*)slo;
    for (int idx = t; idx < 8192; idx += 256) { z1[idx] = 0u; z2[idx] = 0u; }
  }
  __syncthreads();

  const float* Sb = S + (size_t)bb * NOBJ * NOBJ;
  for (int idx = t; idx < NOBJ * NOBJ / 4; idx += 256) {
    const float4 v = ((const float4*)Sb)[idx];
    const int lin = idx * 4, n = lin / NOBJ, m = lin - n * NOBJ;
    const float x[4] = {v.x, v.y, v.z, v.w};
    unsigned h[4], l[4];
#pragma unroll
    for (int e = 0; e < 4; ++e) f16split(x[e], h[e], l[e]);
    const int byte = ((n * 128 + m) * 2) ^ ((n & 7) << 4);
    uint2 hv, lv;
    hv.x = h[0] | (h[1] << 16); hv.y = h[2] | (h[3] << 16);
    lv.x = l[0] | (l[1] << 16); lv.y = l[2] | (l[3] << 16);
    *(uint2*)((char*)shi + byte) = hv;
    *(uint2*)((char*)slo + byte) = lv;
  }
  __syncthreads();

  f32x4 acc[4][2];
#pragma unroll
  for (int i = 0; i < 4; ++i)
#pragma unroll
    for (int j = 0; j < 2; ++j) acc[i][j] = (f32x4){0.f, 0.f, 0.f, 0.f};

#pragma unroll
  for (int ks = 0; ks < 4; ++ks) {
    half8 ah[4], al[4], bv[2];
#pragma unroll
    for (int i = 0; i < 4; ++i) {
      const int row = wr * 64 + i * 16 + lrow;
      const int byte = row * 256 + (((ks * 4 + q) ^ (row & 7)) * 16);
      ah[i] = *(const half8*)((char*)shi + byte);
      al[i] = *(const half8*)((char*)slo + byte);
    }
#pragma unroll
    for (int j = 0; j < 2; ++j) {
      const int brow = wc * 32 + j * 16 + lrow;
      const int byte = brow * 256 + (((ks * 4 + q) ^ (brow & 7)) * 16);
      bv[j] = *(const half8*)((char*)bt + byte);
    }
#pragma unroll
    for (int i = 0; i < 4; ++i)
#pragma unroll
      for (int j = 0; j < 2; ++j) {
        acc[i][j] = __builtin_amdgcn_mfma_f32_16x16x32_f16(ah[i], bv[j], acc[i][j], 0, 0, 0);
        acc[i][j] = __builtin_amdgcn_mfma_f32_16x16x32_f16(al[i], bv[j], acc[i][j], 0, 0, 0);
      }
  }

#pragma unroll
  for (int i = 0; i < 4; ++i) {
    const int row0 = wr * 64 + i * 16 + q * 4;
#pragma unroll
    for (int j = 0; j < 2; ++j) {
      const int col = o0 + wc * 32 + j * 16 + lrow;
#pragma unroll
      for (int r = 0; r < 4; ++r) {
        const int n = row0 + r;
        if (n < NOBJ)
          out[((size_t)bb * NOBJ + n) * 1024 + col] = acc[i][j][r];
      }
    }
  }
}

// ---------------------------------------------------------------------------
// math: out = softmax_n(relu(X (WqWk^T) X^T) .* (G!=0)) @ (X W)
// inputs: feature [256,100,1024] f32 | graph [256,100,100] i32 |
//         weight | wq | wk [1024,1024] f32
// ws (~199 MB): qkhi qklo | opT | wthi wtlo | m1thi m1tlo | wqhi wqlo wkhi
//   wklo | S.  d_out doubles as X hi/lo fp16 staging (dead before agg writes).
// ---------------------------------------------------------------------------
extern "C" void kernel_launch(void* const* d_in, const int* in_sizes, int n_in,
                              void* d_out, int out_size, void* d_ws, size_t ws_size,
                              hipStream_t stream) {
  const float* feature = (const float*)d_in[0];
  const int*   graph   = (const int*)  d_in[1];
  const float* weight  = (const float*)d_in[2];
  const float* wq      = (const float*)d_in[3];
  const float* wk      = (const float*)d_in[4];
  float* out = (float*)d_out;

  const size_t NF = (size_t)25600 * 1024;          // 26,214,400
  const size_t OPT = (size_t)256 * 1024 * 128;     // 33,554,432
  const size_t W1 = (size_t)1024 * 1024;           // 1,048,576
  const size_t need = (2 * NF + OPT + 8 * W1) * 2 + (size_t)2560000 * 4;
  if (ws_size < need) return;                      // fail loudly

  unsigned short* qkhi  = (unsigned short*)d_ws;
  unsigned short* qklo  = qkhi + NF;
  unsigned short* opT   = qklo + NF;
  unsigned short* wthi  = opT + OPT;
  unsigned short* wtlo  = wthi + W1;
  unsigned short* m1thi = wtlo + W1;
  unsigned short* m1tlo = m1thi + W1;
  unsigned short* wqhi  = m1tlo + W1;
  unsigned short* wqlo  = wqhi + W1;
  unsigned short* wkhi  = wqlo + W1;
  unsigned short* wklo  = wkhi + W1;
  float* S = (float*)(wklo + W1);
  unsigned short* xhi = (unsigned short*)d_out;    // d_out as fp16 staging
  unsigned short* xlo = xhi + NF;

  const dim3 blk(256);
  split_ew<<<4096, blk, 0, stream>>>(feature, xhi, xlo, (long long)(NF / 8));
  split_ew<<<512, blk, 0, stream>>>(wq, wqhi, wqlo, (long long)(W1 / 8));
  split_ew<<<512, blk, 0, stream>>>(wk, wkhi, wklo, (long long)(W1 / 8));
  split_tr<<<dim3(32, 32), blk, 0, stream>>>(weight, wthi, wtlo);
  // m1t[n][k] = M1[k][n], M1 = Wq @ Wk^T
  gemm_m1<<<dim3(8, 8), blk, 0, stream>>>(wqhi, wqlo, wkhi, wklo, m1thi, m1tlo);
  // both projections, one launch, XCD-swizzled (3200 = 200 panels x 16 cols)
  proj_gemm<<<3200, blk, 0, stream>>>(xhi, xlo, wthi, wtlo, m1thi, m1tlo,
                                      opT, qkhi, qklo);
  attn_scores_mfma<<<dim3(256), dim3(512), 0, stream>>>(qkhi, qklo, xhi, xlo, graph, S);
  attn_agg_mfma<<<dim3(16, 256), blk, 0, stream>>>(S, opT, out);
}

// Round 9
// 670.035 us; speedup vs baseline: 3.0010x; 1.1133x over previous
//
#include <hip/hip_runtime.h>
#include <cstdint>
#include <cstddef>

#define NOBJ 100

typedef __attribute__((ext_vector_type(8))) _Float16 half8;
typedef __attribute__((ext_vector_type(4))) float f32x4;

typedef const __attribute__((address_space(1))) void* gas_cptr;
typedef __attribute__((address_space(3))) void* las_ptr;

__device__ __forceinline__ void gload_lds16(const void* g, void* l) {
  __builtin_amdgcn_global_load_lds((gas_cptr)g, (las_ptr)l, 16, 0, 0);
}

// ---- fp16 split helpers: x = hi + lo, each fp16 (22-bit combined mantissa) ----
__device__ __forceinline__ unsigned short f16h(float x) {
  return __builtin_bit_cast(unsigned short, (_Float16)x);
}
__device__ __forceinline__ void f16split(float x, unsigned& h, unsigned& l) {
  _Float16 hh = (_Float16)x;
  _Float16 ll = (_Float16)(x - (float)hh);
  h = (unsigned)__builtin_bit_cast(unsigned short, hh);
  l = (unsigned)__builtin_bit_cast(unsigned short, ll);
}

// ---------------------------------------------------------------------------
// split_ew: f32[n] -> hi fp16[n], lo fp16[n].  n8 = n/8.
// ---------------------------------------------------------------------------
__global__ __launch_bounds__(256)
void split_ew(const float* __restrict__ in, unsigned short* __restrict__ hi,
              unsigned short* __restrict__ lo, long long n8) {
  for (long long u = (long long)blockIdx.x * 256 + threadIdx.x; u < n8;
       u += (long long)gridDim.x * 256) {
    const float4* p = (const float4*)(in + u * 8);
    float4 v0 = p[0], v1 = p[1];
    float x[8] = {v0.x, v0.y, v0.z, v0.w, v1.x, v1.y, v1.z, v1.w};
    unsigned h[8], l[8];
#pragma unroll
    for (int j = 0; j < 8; ++j) f16split(x[j], h[j], l[j]);
    uint4 hv, lv;
    hv.x = h[0] | (h[1] << 16); hv.y = h[2] | (h[3] << 16);
    hv.z = h[4] | (h[5] << 16); hv.w = h[6] | (h[7] << 16);
    lv.x = l[0] | (l[1] << 16); lv.y = l[2] | (l[3] << 16);
    lv.z = l[4] | (l[5] << 16); lv.w = l[6] | (l[7] << 16);
    *(uint4*)(hi + u * 8) = hv;
    *(uint4*)(lo + u * 8) = lv;
  }
}

// ---------------------------------------------------------------------------
// split_tr: W f32 [1024][1024] -> Wt hi/lo fp16 [1024][1024] transposed.
// ---------------------------------------------------------------------------
__global__ __launch_bounds__(256)
void split_tr(const float* __restrict__ W, unsigned short* __restrict__ thi,
              unsigned short* __restrict__ tlo) {
  __shared__ float tile[32][33];
  const int r0 = blockIdx.y * 32, c0 = blockIdx.x * 32;
  const int tx = threadIdx.x & 31, ty = threadIdx.x >> 5;
  for (int rr = ty; rr < 32; rr += 8)
    tile[rr][tx] = W[(size_t)(r0 + rr) * 1024 + c0 + tx];
  __syncthreads();
  for (int cc = ty; cc < 32; cc += 8) {
    float x = tile[tx][cc];
    unsigned h, l;
    f16split(x, h, l);
    size_t o = (size_t)(c0 + cc) * 1024 + r0 + tx;
    thi[o] = (unsigned short)h;
    tlo[o] = (unsigned short)l;
  }
}

// ---------------------------------------------------------------------------
// gemm_m1: m1t[n][k] = M1[k][n],  M1 = Wq @ Wk^T, fp16 hi/lo 3-MFMA.
// A = wq splits [1024][1024], B = wk splits [1024][1024]. Grid (8,8).
// (Feeds the exp-sensitive alpha path -> keep full 3-MFMA precision.)
// ---------------------------------------------------------------------------
__global__ __launch_bounds__(256)
void gemm_m1(const unsigned short* __restrict__ Ah, const unsigned short* __restrict__ Al,
             const unsigned short* __restrict__ Bh, const unsigned short* __restrict__ Bl,
             unsigned short* __restrict__ Th, unsigned short* __restrict__ Tl) {
  __shared__ unsigned short s_ah[4096], s_al[4096], s_bh[4096], s_bl[4096];
  const int t = threadIdx.x;
  const int wid = t >> 6, lane = t & 63;
  const int wr = wid >> 1, wc = wid & 1;
  const int lrow = lane & 15, q = lane >> 4;
  const int m0 = blockIdx.y * 128, n0 = blockIdx.x * 128;

  const int srow = t >> 2;
  const int skch = (t & 3) ^ ((t >> 3) & 3);
  const unsigned short* gAh = Ah + (size_t)(m0 + srow) * 1024 + skch * 8;
  const unsigned short* gAl = Al + (size_t)(m0 + srow) * 1024 + skch * 8;
  const unsigned short* gBh = Bh + (size_t)(n0 + srow) * 1024 + skch * 8;
  const unsigned short* gBl = Bl + (size_t)(n0 + srow) * 1024 + skch * 8;
  const size_t rstep = (size_t)64 * 1024;
  unsigned short* dA0  = &s_ah[wid * 512];
  unsigned short* dA1  = &s_ah[wid * 512 + 2048];
  unsigned short* dAl0 = &s_al[wid * 512];
  unsigned short* dAl1 = &s_al[wid * 512 + 2048];
  unsigned short* dB0  = &s_bh[wid * 512];
  unsigned short* dB1  = &s_bh[wid * 512 + 2048];
  unsigned short* dBl0 = &s_bl[wid * 512];
  unsigned short* dBl1 = &s_bl[wid * 512 + 2048];
  const int fq = (q ^ ((lrow >> 1) & 3)) * 8;

  f32x4 acc[4][4];
#pragma unroll
  for (int i = 0; i < 4; ++i)
#pragma unroll
    for (int j = 0; j < 4; ++j) acc[i][j] = (f32x4){0.f, 0.f, 0.f, 0.f};

  for (int kc = 0; kc < 1024; kc += 32) {
    gload_lds16(gAh + kc, dA0);
    gload_lds16(gAh + kc + rstep, dA1);
    gload_lds16(gAl + kc, dAl0);
    gload_lds16(gAl + kc + rstep, dAl1);
    gload_lds16(gBh + kc, dB0);
    gload_lds16(gBh + kc + rstep, dB1);
    gload_lds16(gBl + kc, dBl0);
    gload_lds16(gBl + kc + rstep, dBl1);
    __syncthreads();
    half8 a_h[4], a_l[4];
#pragma unroll
    for (int i = 0; i < 4; ++i) {
      const int ra = (wr * 64 + i * 16 + lrow) * 32 + fq;
      a_h[i] = *(const half8*)&s_ah[ra];
      a_l[i] = *(const half8*)&s_al[ra];
    }
#pragma unroll
    for (int j = 0; j < 4; ++j) {
      const int rb = (wc * 64 + j * 16 + lrow) * 32 + fq;
      half8 b_h = *(const half8*)&s_bh[rb];
      half8 b_l = *(const half8*)&s_bl[rb];
#pragma unroll
      for (int i = 0; i < 4; ++i) {
        acc[i][j] = __builtin_amdgcn_mfma_f32_16x16x32_f16(a_h[i], b_h, acc[i][j], 0, 0, 0);
        acc[i][j] = __builtin_amdgcn_mfma_f32_16x16x32_f16(a_h[i], b_l, acc[i][j], 0, 0, 0);
        acc[i][j] = __builtin_amdgcn_mfma_f32_16x16x32_f16(a_l[i], b_h, acc[i][j], 0, 0, 0);
      }
    }
    __syncthreads();
  }

  // C/D layout: col = lane&15, row = (lane>>4)*4 + reg; store transposed hi/lo
#pragma unroll
  for (int i = 0; i < 4; ++i) {
    const int row0 = m0 + wr * 64 + i * 16 + q * 4;
#pragma unroll
    for (int j = 0; j < 4; ++j) {
      const int col = n0 + wc * 64 + j * 16 + lrow;
      unsigned h[4], l[4];
#pragma unroll
      for (int r = 0; r < 4; ++r) f16split(acc[i][j][r], h[r], l[r]);
      uint2 hv, lv;
      hv.x = h[0] | (h[1] << 16); hv.y = h[2] | (h[3] << 16);
      lv.x = l[0] | (l[1] << 16); lv.y = l[2] | (l[3] << 16);
      *(uint2*)(Th + (size_t)col * 1024 + row0) = hv;
      *(uint2*)(Tl + (size_t)col * 1024 + row0) = lv;
    }
  }
}

// ---------------------------------------------------------------------------
// proj_gemm: BOTH projections in one launch, XCD-swizzled.
//   wgid = (bid%8)*400 + bid/8; row-panel = wgid/16; col-block = wgid%16.
//   col-block < 8:  C = X @ W   -> opT (fp16 hi only).  Since the OUTPUT is
//     rounded to fp16 anyway, compute with 1 MFMA (hh) and skip staging the
//     lo panels entirely: added error ~2^-10 rel ~ 1e-3 abs in final out.
//   col-block >= 8: C = X @ M1  -> qk hi/lo (exp-sensitive: full 3-MFMA).
// All 16 col-blocks of one A panel land on ONE XCD -> A fetched once.
// 128x128 tile, BK=32, XOR slot swizzle both sides.
// ---------------------------------------------------------------------------
__global__ __launch_bounds__(256)
void proj_gemm(const unsigned short* __restrict__ Ah, const unsigned short* __restrict__ Al,
               const unsigned short* __restrict__ Wh, const unsigned short* __restrict__ Wl,
               const unsigned short* __restrict__ Mh, const unsigned short* __restrict__ Ml,
               unsigned short* __restrict__ opT, unsigned short* __restrict__ qkh,
               unsigned short* __restrict__ qkl) {
  __shared__ unsigned short s_ah[4096], s_al[4096], s_bh[4096], s_bl[4096];
  const int t = threadIdx.x;
  const int wid = t >> 6, lane = t & 63;
  const int wr = wid >> 1, wc = wid & 1;
  const int lrow = lane & 15, q = lane >> 4;

  const int bid  = blockIdx.x;
  const int wgid = (bid & 7) * 400 + (bid >> 3);   // bijective: 3200 % 8 == 0
  const int m0   = (wgid >> 4) * 128;
  const int cb   = wgid & 15;
  const bool isW = cb < 8;
  const int n0   = (isW ? cb : cb - 8) * 128;
  const unsigned short* Bh = isW ? Wh : Mh;
  const unsigned short* Bl = isW ? Wl : Ml;

  const int srow = t >> 2;
  const int skch = (t & 3) ^ ((t >> 3) & 3);
  const unsigned short* gAh = Ah + (size_t)(m0 + srow) * 1024 + skch * 8;
  const unsigned short* gAl = Al + (size_t)(m0 + srow) * 1024 + skch * 8;
  const unsigned short* gBh = Bh + (size_t)(n0 + srow) * 1024 + skch * 8;
  const unsigned short* gBl = Bl + (size_t)(n0 + srow) * 1024 + skch * 8;
  const size_t rstep = (size_t)64 * 1024;
  unsigned short* dA0  = &s_ah[wid * 512];
  unsigned short* dA1  = &s_ah[wid * 512 + 2048];
  unsigned short* dAl0 = &s_al[wid * 512];
  unsigned short* dAl1 = &s_al[wid * 512 + 2048];
  unsigned short* dB0  = &s_bh[wid * 512];
  unsigned short* dB1  = &s_bh[wid * 512 + 2048];
  unsigned short* dBl0 = &s_bl[wid * 512];
  unsigned short* dBl1 = &s_bl[wid * 512 + 2048];
  const int fq = (q ^ ((lrow >> 1) & 3)) * 8;

  f32x4 acc[4][4];
#pragma unroll
  for (int i = 0; i < 4; ++i)
#pragma unroll
    for (int j = 0; j < 4; ++j) acc[i][j] = (f32x4){0.f, 0.f, 0.f, 0.f};

  if (isW) {
    // ---- hh-only K-loop: 4 gloads + 16 MFMA per BK=32 step ----
    for (int kc = 0; kc < 1024; kc += 32) {
      gload_lds16(gAh + kc, dA0);
      gload_lds16(gAh + kc + rstep, dA1);
      gload_lds16(gBh + kc, dB0);
      gload_lds16(gBh + kc + rstep, dB1);
      __syncthreads();
      half8 a_h[4];
#pragma unroll
      for (int i = 0; i < 4; ++i) {
        const int ra = (wr * 64 + i * 16 + lrow) * 32 + fq;
        a_h[i] = *(const half8*)&s_ah[ra];
      }
#pragma unroll
      for (int j = 0; j < 4; ++j) {
        const int rb = (wc * 64 + j * 16 + lrow) * 32 + fq;
        half8 b_h = *(const half8*)&s_bh[rb];
#pragma unroll
        for (int i = 0; i < 4; ++i)
          acc[i][j] = __builtin_amdgcn_mfma_f32_16x16x32_f16(a_h[i], b_h, acc[i][j], 0, 0, 0);
      }
      __syncthreads();
    }
  } else {
    // ---- full hi/lo 3-MFMA K-loop (alpha path) ----
    for (int kc = 0; kc < 1024; kc += 32) {
      gload_lds16(gAh + kc, dA0);
      gload_lds16(gAh + kc + rstep, dA1);
      gload_lds16(gAl + kc, dAl0);
      gload_lds16(gAl + kc + rstep, dAl1);
      gload_lds16(gBh + kc, dB0);
      gload_lds16(gBh + kc + rstep, dB1);
      gload_lds16(gBl + kc, dBl0);
      gload_lds16(gBl + kc + rstep, dBl1);
      __syncthreads();
      half8 a_h[4], a_l[4];
#pragma unroll
      for (int i = 0; i < 4; ++i) {
        const int ra = (wr * 64 + i * 16 + lrow) * 32 + fq;
        a_h[i] = *(const half8*)&s_ah[ra];
        a_l[i] = *(const half8*)&s_al[ra];
      }
#pragma unroll
      for (int j = 0; j < 4; ++j) {
        const int rb = (wc * 64 + j * 16 + lrow) * 32 + fq;
        half8 b_h = *(const half8*)&s_bh[rb];
        half8 b_l = *(const half8*)&s_bl[rb];
#pragma unroll
        for (int i = 0; i < 4; ++i) {
          acc[i][j] = __builtin_amdgcn_mfma_f32_16x16x32_f16(a_h[i], b_h, acc[i][j], 0, 0, 0);
          acc[i][j] = __builtin_amdgcn_mfma_f32_16x16x32_f16(a_h[i], b_l, acc[i][j], 0, 0, 0);
          acc[i][j] = __builtin_amdgcn_mfma_f32_16x16x32_f16(a_l[i], b_h, acc[i][j], 0, 0, 0);
        }
      }
      __syncthreads();
    }
  }

#pragma unroll
  for (int i = 0; i < 4; ++i) {
    const int row0 = m0 + wr * 64 + i * 16 + q * 4;   // mult of 4; 100%4==0 ->
#pragma unroll                                        // never straddles batch
    for (int j = 0; j < 4; ++j) {
      const int col = n0 + wc * 64 + j * 16 + lrow;
      if (isW) {
        unsigned h[4];
#pragma unroll
        for (int r = 0; r < 4; ++r) h[r] = (unsigned)f16h(acc[i][j][r]);
        const unsigned bb = (unsigned)row0 / 100u;
        const unsigned ml = (unsigned)row0 - bb * 100u;
        uint2 hv;
        hv.x = h[0] | (h[1] << 16);
        hv.y = h[2] | (h[3] << 16);
        *(uint2*)(opT + ((size_t)bb * 1024 + col) * 128 + ml) = hv;
      } else {
        unsigned h[4], l[4];
#pragma unroll
        for (int r = 0; r < 4; ++r) f16split(acc[i][j][r], h[r], l[r]);
#pragma unroll
        for (int r = 0; r < 4; ++r) {
          const size_t o = (size_t)(row0 + r) * 1024 + col;
          qkh[o] = (unsigned short)h[r];
          qkl[o] = (unsigned short)l[r];
        }
      }
    }
  }
}

// ---------------------------------------------------------------------------
// attn_scores_mfma: per-batch S = relu(qk_b @ X_b^T) .* (graph!=0), softmax
// over n (masked zeros participate).  512 threads / 8 waves (2x4), per-wave
// 64x32 tile, fp16 hi/lo 3-MFMA, K=1024 in BK=32 steps.  Pad rows (100..127)
// clamp to row 99 on the per-lane *source* address; results discarded.
// LDS: 4x8KB staging + 40KB scores = 72.7 KB.
// ---------------------------------------------------------------------------
__global__ __launch_bounds__(512)
void attn_scores_mfma(const unsigned short* __restrict__ Qh, const unsigned short* __restrict__ Ql,
                      const unsigned short* __restrict__ Xh, const unsigned short* __restrict__ Xl,
                      const int* __restrict__ graph, float* __restrict__ S) {
  __shared__ unsigned short s_ah[4096], s_al[4096], s_bh[4096], s_bl[4096];
  __shared__ float s[NOBJ * NOBJ];
  const int t = threadIdx.x;
  const int wid = t >> 6, lane = t & 63;
  const int wr = wid >> 2, wc = wid & 3;
  const int lrow = lane & 15, q = lane >> 4;
  const int bb = blockIdx.x;

  const int srow = t >> 2;                         // 0..127
  const int rc   = srow < NOBJ ? srow : (NOBJ - 1);
  const int skch = (t & 3) ^ ((t >> 3) & 3);
  const size_t base = (size_t)bb * NOBJ * 1024;
  const unsigned short* gQh = Qh + base + (size_t)rc * 1024 + skch * 8;
  const unsigned short* gQl = Ql + base + (size_t)rc * 1024 + skch * 8;
  const unsigned short* gXh = Xh + base + (size_t)rc * 1024 + skch * 8;
  const unsigned short* gXl = Xl + base + (size_t)rc * 1024 + skch * 8;
  unsigned short* dQh = &s_ah[wid * 512];          // wave-uniform bases
  unsigned short* dQl = &s_al[wid * 512];
  unsigned short* dXh = &s_bh[wid * 512];
  unsigned short* dXl = &s_bl[wid * 512];
  const int fq = (q ^ ((lrow >> 1) & 3)) * 8;

  f32x4 acc[4][2];
#pragma unroll
  for (int i = 0; i < 4; ++i)
#pragma unroll
    for (int j = 0; j < 2; ++j) acc[i][j] = (f32x4){0.f, 0.f, 0.f, 0.f};

  for (int kc = 0; kc < 1024; kc += 32) {
    gload_lds16(gQh + kc, dQh);
    gload_lds16(gQl + kc, dQl);
    gload_lds16(gXh + kc, dXh);
    gload_lds16(gXl + kc, dXl);
    __syncthreads();
    half8 a_h[4], a_l[4];
#pragma unroll
    for (int i = 0; i < 4; ++i) {
      const int ra = (wr * 64 + i * 16 + lrow) * 32 + fq;
      a_h[i] = *(const half8*)&s_ah[ra];
      a_l[i] = *(const half8*)&s_al[ra];
    }
#pragma unroll
    for (int j = 0; j < 2; ++j) {
      const int rb = (wc * 32 + j * 16 + lrow) * 32 + fq;
      half8 b_h = *(const half8*)&s_bh[rb];
      half8 b_l = *(const half8*)&s_bl[rb];
#pragma unroll
      for (int i = 0; i < 4; ++i) {
        acc[i][j] = __builtin_amdgcn_mfma_f32_16x16x32_f16(a_h[i], b_h, acc[i][j], 0, 0, 0);
        acc[i][j] = __builtin_amdgcn_mfma_f32_16x16x32_f16(a_h[i], b_l, acc[i][j], 0, 0, 0);
        acc[i][j] = __builtin_amdgcn_mfma_f32_16x16x32_f16(a_l[i], b_h, acc[i][j], 0, 0, 0);
      }
    }
    __syncthreads();
  }

  // relu + adjacency mask -> s (valid region only)
  const int* gb = graph + (size_t)bb * NOBJ * NOBJ;
#pragma unroll
  for (int i = 0; i < 4; ++i) {
    const int row0 = wr * 64 + i * 16 + q * 4;
#pragma unroll
    for (int j = 0; j < 2; ++j) {
      const int col = wc * 32 + j * 16 + lrow;
      if (col < NOBJ) {
#pragma unroll
        for (int r = 0; r < 4; ++r) {
          const int n = row0 + r;
          if (n < NOBJ) {
            float v = acc[i][j][r];
            v = v > 0.f ? v : 0.f;
            s[n * NOBJ + col] = (gb[n * NOBJ + col] != 0) ? v : 0.f;
          }
        }
      }
    }
  }
  __syncthreads();

  if (t < NOBJ) {   // softmax over n for column m=t (values >=0 -> max seed 0)
    const int m = t;
    float mx = 0.f;
    for (int n = 0; n < NOBJ; ++n) mx = fmaxf(mx, s[n * NOBJ + m]);
    float sum = 0.f;
    for (int n = 0; n < NOBJ; ++n) {
      const float e = expf(s[n * NOBJ + m] - mx);
      s[n * NOBJ + m] = e;
      sum += e;
    }
    const float inv = 1.f / sum;
    for (int n = 0; n < NOBJ; ++n) s[n * NOBJ + m] *= inv;
  }
  __syncthreads();

  float* Sb = S + (size_t)bb * NOBJ * NOBJ;
  for (int idx = t; idx < NOBJ * NOBJ; idx += 512) Sb[idx] = s[idx];
}

// ---------------------------------------------------------------------------
// attn_agg_mfma: out[b,n,:] = sum_m S~[n][m] * outp[m,:] via fp16 MFMA.
// A = S hi/lo (f32->split in LDS, XOR-swizzled, k-pad m=100..127 ZEROED,
// which annihilates opT's unwritten pad columns).  B = opT rows, staged via
// gload_lds with pre-swizzled source.  Grid (16, 256): o-chunk 64 x batch.
// ---------------------------------------------------------------------------
__global__ __launch_bounds__(256)
void attn_agg_mfma(const float* __restrict__ S, const unsigned short* __restrict__ opT,
                   float* __restrict__ out) {
  __shared__ unsigned short shi[128 * 128];
  __shared__ unsigned short slo[128 * 128];
  __shared__ unsigned short bt[64 * 128];
  const int t = threadIdx.x;
  const int wid = t >> 6, lane = t & 63;
  const int wr = wid >> 1, wc = wid & 1;
  const int lrow = lane & 15, q = lane >> 4;
  const int bb = blockIdx.y, o0 = blockIdx.x * 64;

#pragma unroll
  for (int p = 0; p < 4; ++p) {
    const int u = p * 256 + t;
    const int row = u >> 4, sl = u & 15;
    const int sp = sl ^ (row & 7);
    gload_lds16(opT + ((size_t)(bb * 1024 + o0 + row)) * 128 + sp * 8,
                bt + (p * 256 + wid * 64) * 8);
  }

  {
    unsigned* z1 = (unsigned*)shi;
    unsigned* z2 = (unsigned*)slo;
    for (int idx = t; idx < 8192; idx += 256) { z1[idx] = 0u; z2[idx] = 0u; }
  }
  __syncthreads();

  const float* Sb = S + (size_t)bb * NOBJ * NOBJ;
  for (int idx = t; idx < NOBJ * NOBJ / 4; idx += 256) {
    const float4 v = ((const float4*)Sb)[idx];
    const int lin = idx * 4, n = lin / NOBJ, m = lin - n * NOBJ;
    const float x[4] = {v.x, v.y, v.z, v.w};
    unsigned h[4], l[4];
#pragma unroll
    for (int e = 0; e < 4; ++e) f16split(x[e], h[e], l[e]);
    const int byte = ((n * 128 + m) * 2) ^ ((n & 7) << 4);
    uint2 hv, lv;
    hv.x = h[0] | (h[1] << 16); hv.y = h[2] | (h[3] << 16);
    lv.x = l[0] | (l[1] << 16); lv.y = l[2] | (l[3] << 16);
    *(uint2*)((char*)shi + byte) = hv;
    *(uint2*)((char*)slo + byte) = lv;
  }
  __syncthreads();

  f32x4 acc[4][2];
#pragma unroll
  for (int i = 0; i < 4; ++i)
#pragma unroll
    for (int j = 0; j < 2; ++j) acc[i][j] = (f32x4){0.f, 0.f, 0.f, 0.f};

#pragma unroll
  for (int ks = 0; ks < 4; ++ks) {
    half8 ah[4], al[4], bv[2];
#pragma unroll
    for (int i = 0; i < 4; ++i) {
      const int row = wr * 64 + i * 16 + lrow;
      const int byte = row * 256 + (((ks * 4 + q) ^ (row & 7)) * 16);
      ah[i] = *(const half8*)((char*)shi + byte);
      al[i] = *(const half8*)((char*)slo + byte);
    }
#pragma unroll
    for (int j = 0; j < 2; ++j) {
      const int brow = wc * 32 + j * 16 + lrow;
      const int byte = brow * 256 + (((ks * 4 + q) ^ (brow & 7)) * 16);
      bv[j] = *(const half8*)((char*)bt + byte);
    }
#pragma unroll
    for (int i = 0; i < 4; ++i)
#pragma unroll
      for (int j = 0; j < 2; ++j) {
        acc[i][j] = __builtin_amdgcn_mfma_f32_16x16x32_f16(ah[i], bv[j], acc[i][j], 0, 0, 0);
        acc[i][j] = __builtin_amdgcn_mfma_f32_16x16x32_f16(al[i], bv[j], acc[i][j], 0, 0, 0);
      }
  }

#pragma unroll
  for (int i = 0; i < 4; ++i) {
    const int row0 = wr * 64 + i * 16 + q * 4;
#pragma unroll
    for (int j = 0; j < 2; ++j) {
      const int col = o0 + wc * 32 + j * 16 + lrow;
#pragma unroll
      for (int r = 0; r < 4; ++r) {
        const int n = row0 + r;
        if (n < NOBJ)
          out[((size_t)bb * NOBJ + n) * 1024 + col] = acc[i][j][r];
      }
    }
  }
}

// ---------------------------------------------------------------------------
// math: out = softmax_n(relu(X (WqWk^T) X^T) .* (G!=0)) @ (X W)
// inputs: feature [256,100,1024] f32 | graph [256,100,100] i32 |
//         weight | wq | wk [1024,1024] f32
// ws (~199 MB): qkhi qklo | opT | wthi wtlo | m1thi m1tlo | wqhi wqlo wkhi
//   wklo | S.  d_out doubles as X hi/lo fp16 staging (dead before agg writes).
// ---------------------------------------------------------------------------
extern "C" void kernel_launch(void* const* d_in, const int* in_sizes, int n_in,
                              void* d_out, int out_size, void* d_ws, size_t ws_size,
                              hipStream_t stream) {
  const float* feature = (const float*)d_in[0];
  const int*   graph   = (const int*)  d_in[1];
  const float* weight  = (const float*)d_in[2];
  const float* wq      = (const float*)d_in[3];
  const float* wk      = (const float*)d_in[4];
  float* out = (float*)d_out;

  const size_t NF = (size_t)25600 * 1024;          // 26,214,400
  const size_t OPT = (size_t)256 * 1024 * 128;     // 33,554,432
  const size_t W1 = (size_t)1024 * 1024;           // 1,048,576
  const size_t need = (2 * NF + OPT + 8 * W1) * 2 + (size_t)2560000 * 4;
  if (ws_size < need) return;                      // fail loudly

  unsigned short* qkhi  = (unsigned short*)d_ws;
  unsigned short* qklo  = qkhi + NF;
  unsigned short* opT   = qklo + NF;
  unsigned short* wthi  = opT + OPT;
  unsigned short* wtlo  = wthi + W1;
  unsigned short* m1thi = wtlo + W1;
  unsigned short* m1tlo = m1thi + W1;
  unsigned short* wqhi  = m1tlo + W1;
  unsigned short* wqlo  = wqhi + W1;
  unsigned short* wkhi  = wqlo + W1;
  unsigned short* wklo  = wkhi + W1;
  float* S = (float*)(wklo + W1);
  unsigned short* xhi = (unsigned short*)d_out;    // d_out as fp16 staging
  unsigned short* xlo = xhi + NF;

  const dim3 blk(256);
  split_ew<<<4096, blk, 0, stream>>>(feature, xhi, xlo, (long long)(NF / 8));
  split_ew<<<512, blk, 0, stream>>>(wq, wqhi, wqlo, (long long)(W1 / 8));
  split_ew<<<512, blk, 0, stream>>>(wk, wkhi, wklo, (long long)(W1 / 8));
  split_tr<<<dim3(32, 32), blk, 0, stream>>>(weight, wthi, wtlo);
  // m1t[n][k] = M1[k][n], M1 = Wq @ Wk^T
  gemm_m1<<<dim3(8, 8), blk, 0, stream>>>(wqhi, wqlo, wkhi, wklo, m1thi, m1tlo);
  // both projections, one launch, XCD-swizzled (3200 = 200 panels x 16 cols)
  proj_gemm<<<3200, blk, 0, stream>>>(xhi, xlo, wthi, wtlo, m1thi, m1tlo,
                                      opT, qkhi, qklo);
  attn_scores_mfma<<<dim3(256), dim3(512), 0, stream>>>(qkhi, qklo, xhi, xlo, graph, S);
  attn_agg_mfma<<<dim3(16, 256), blk, 0, stream>>>(S, opT, out);
}